// Round 12
// baseline (607.350 us; speedup 1.0000x reference)
//
#include <hip/hip_runtime.h>

#define NN    50000
#define DD    128
#define RR    3
#define EE    800000
#define OUTD  64
#define BKT   128                 // nodes per bucket (dst binning)
#define NBK   391                 // ceil(NN/BKT)
#define CAP   2560                // per-bucket edge capacity, 4B dst-entries
#define CAPB  2560                // (layout only)
#define CHUNK 8192                // edges per bin block
#define NCH   98                  // ceil(EE/CHUNK)
#define NBINA (RR * NCH)          // 294 dst-bin blocks
#define DEGB  (RR * 2)            // 6 out-degree histogram blocks (2 per relation, 25K nodes each)
#define DEGN  25000               // nodes per deg block
#define CASTB 6250                // NN*DD/4/256 cast blocks
#define NPB   3125                // NN/16 pull blocks per relation
#define PGB   391                 // ceil(NN/128) pgemm blocks
#define P64B  3125                // NN/16 pull64 blocks
#define ALPHA_ 0.5f
#define SLOPE_ 0.01f
#define BETA1_ 0.6931471805599453f   // log(2)
#define BETA2_ 0.4054651081081644f   // log(1.5)

typedef __attribute__((ext_vector_type(8))) short short8;   // 8 bf16 = 4 VGPRs
typedef __attribute__((ext_vector_type(4))) float f32x4;
typedef __attribute__((ext_vector_type(4))) unsigned int u32x4;

__device__ __forceinline__ unsigned short f2b(float f) {   // fp32 -> bf16 RNE
    unsigned int u = __builtin_bit_cast(unsigned int, f);
    u += 0x7FFFu + ((u >> 16) & 1u);
    return (unsigned short)(u >> 16);
}
__device__ __forceinline__ unsigned int pack2(float lo, float hi) {
    return (unsigned int)f2b(lo) | ((unsigned int)f2b(hi) << 16);
}
__device__ __forceinline__ float blo(unsigned int w) { return __builtin_bit_cast(float, w << 16); }
__device__ __forceinline__ float bhi(unsigned int w) { return __builtin_bit_cast(float, w & 0xFFFF0000u); }

// ---------------- bin+deg: dst-binning | out-degree LDS histogram (50KB union, 2 blocks/CU) ------
//  [0, NBINA)        : dst-phase LDS bucket-sort (round-6-verified logic, 1024 threads, 39KB)
//  [NBINA, +DEGB)    : out-degree histogram, 2 blocks/relation x 25K nodes packed u16 (50KB);
//                      each scans all 800K srcs with a range filter — zero global atomics.
// Round-11 lesson: merged roles share ONE static LDS size; keep the 100KB role out so the
// union is 50KB and all 300 blocks stay co-resident.
__global__ __launch_bounds__(1024) void bin_deg_kernel(
    const int* __restrict__ src, const int* __restrict__ dst,
    int* __restrict__ bcnt_d, int* __restrict__ pairs_d,
    float* __restrict__ dego_r)
{
    __shared__ unsigned int shmem[12800];    // 51200 B union
    const int tid = threadIdx.x;
    const int blk = blockIdx.x;

    if (blk < NBINA) {
        // ---- dst-phase binning (CHUNK=8192, 1024 threads) ----
        unsigned int* hist    = shmem;               // [NBK]
        unsigned int* lbase   = shmem + NBK;         // [NBK]
        unsigned int* gdelta  = shmem + 2 * NBK;     // [NBK]
        unsigned int* lcur    = shmem + 3 * NBK;     // [NBK]
        unsigned int* staging = shmem + 4 * NBK;     // [CHUNK]
        const int r = blk / NCH;
        const int chunk = blk % NCH;
        const int e0 = chunk * CHUNK;
        const int n = min(CHUNK, EE - e0);
        const int* sp = src + (size_t)r * EE + e0;
        const int* dp = dst + (size_t)r * EE + e0;

        for (int i = tid; i < NBK; i += 1024) hist[i] = 0;
        __syncthreads();
        for (int i = tid; i < n; i += 1024)
            atomicAdd(&hist[dp[i] >> 7], 1u);
        __syncthreads();
        if (tid < 64) {
            int carry = 0;
            for (int c0 = 0; c0 < NBK; c0 += 64) {
                const int idx = c0 + tid;
                const int v = (idx < NBK) ? (int)hist[idx] : 0;
                int incl = v;
                #pragma unroll
                for (int d = 1; d < 64; d <<= 1) {
                    const int t = __shfl_up(incl, d, 64);
                    if (tid >= d) incl += t;
                }
                if (idx < NBK) lbase[idx] = carry + incl - v;
                carry += __shfl(incl, 63, 64);
            }
        }
        __syncthreads();
        for (int b = tid; b < NBK; b += 1024) {
            lcur[b] = lbase[b];
            const int h = (int)hist[b];
            if (h > 0) {
                const int gstart = (r * NBK + b) * CAP + atomicAdd(&bcnt_d[r * NBK + b], h);
                gdelta[b] = (unsigned int)(gstart - (int)lbase[b]);
            }
        }
        __syncthreads();
        for (int i = tid; i < n; i += 1024) {
            const int d = dp[i];
            const int b = d >> 7;
            const int pos = atomicAdd(&lcur[b], 1u);
            staging[pos] = (unsigned int)sp[i] | ((unsigned int)(d & 127) << 16)
                         | ((unsigned int)b << 23);
        }
        __syncthreads();
        for (int j = tid; j < n; j += 1024) {
            const unsigned int v = staging[j];
            const int b = v >> 23;
            const int gi = (int)gdelta[b] + j;
            const int lo = gi - (r * NBK + b) * CAP;
            if (lo < CAP) pairs_d[gi] = (int)(v & 0x7FFFFF);
        }
    } else {
        // ---- out-degree histogram: relation r, node range [base, base+DEGN) ----
        const int t = blk - NBINA;               // 0..5
        const int r = t >> 1;
        const int base = (t & 1) * DEGN;
        for (int i = tid; i < DEGN / 2; i += 1024) shmem[i] = 0;
        __syncthreads();
        const int* sp = src + (size_t)r * EE;
        for (int e = tid; e < EE; e += 1024) {
            const int s = sp[e] - base;
            if ((unsigned)s < (unsigned)DEGN)
                atomicAdd(&shmem[s >> 1], 1u << ((s & 1) * 16));
        }
        __syncthreads();
        for (int g = tid; g < DEGN; g += 1024) {
            const int cnt = (int)((shmem[g >> 1] >> ((g & 1) * 16)) & 0xFFFFu);
            dego_r[r * NN + base + g] = rsqrtf((float)max(cnt, 1));
        }
    }
}

// ---------------- cast: x -> bf16 | W1'/W2' prep | M_r = W2'@Wlin/3 (transposed) | C vector ------
// 256 threads, no LDS -> full occupancy streaming (round-11 lesson: keep away from big-LDS roles).
__global__ __launch_bounds__(256) void cast_kernel(
    const float* __restrict__ x, unsigned short* __restrict__ xb,
    const float* __restrict__ W1, const float* __restrict__ W2,
    const float* __restrict__ Wlin, unsigned short* __restrict__ Wt1,
    unsigned short* __restrict__ Wt2,
    const float* __restrict__ b2, const float* __restrict__ blin,
    unsigned short* __restrict__ MT, float* __restrict__ Cbuf)
{
    const int i = blockIdx.x * 256 + threadIdx.x;   // 0 .. NN*DD/4-1
    {
        const float4 v = ((const float4*)x)[i];
        ushort4 o;
        o.x = f2b(v.x); o.y = f2b(v.y); o.z = f2b(v.z); o.w = f2b(v.w);
        ((ushort4*)xb)[i] = o;
    }
    if (i < RR * DD * DD) {
        const int r = i >> 14, rem = i & 16383, nn = rem >> 7, k = rem & 127;
        const float diag = (k == nn) ? 1.0f : 0.0f;
        const float w1 = W1[r * DD * DD + k * DD + nn];
        Wt1[i] = f2b(BETA1_ * w1 + diag * (1.0f - BETA1_));
        const float w2 = W2[r * DD * DD + k * DD + nn];
        Wt2[i] = f2b((BETA2_ * w2 + diag * (1.0f - BETA2_)) * (1.0f / 3.0f));
    }
    if (i < RR * OUTD * DD) {
        // M_r^T[o][k] = ((1-b2)/3)*Wlin[k][o] + (b2/3)*sum_n W2[r][k][n]*Wlin[n][o]
        const int r = i >> 13;
        const int rem = i & 8191;
        const int o = rem >> 7, k = rem & 127;
        float s = 0.f;
        for (int nn = 0; nn < DD; ++nn)
            s += W2[r * DD * DD + k * DD + nn] * Wlin[nn * OUTD + o];
        MT[i] = f2b((BETA2_ / 3.0f) * s + ((1.0f - BETA2_) / 3.0f) * Wlin[k * OUTD + o]);
    }
    if (i < OUTD) {
        float s = blin[i];
        for (int nn = 0; nn < DD; ++nn) {
            const float mb2 = (b2[nn] + b2[DD + nn] + b2[2 * DD + nn]) * (1.0f / 3.0f);
            s += mb2 * Wlin[nn * OUTD + i];
        }
        Cbuf[i] = s;
    }
}

// ---------------- per-bucket counting sort (in place) -> weighted CSR + degi ----------------
__global__ __launch_bounds__(256) void sort_kernel(
    int* __restrict__ pairs_d, const int* __restrict__ bcnt_d,
    const float* __restrict__ dego_r,
    int* __restrict__ off_g, int* __restrict__ cnt_g, float* __restrict__ degi_r)
{
    __shared__ int stage[CAP];
    __shared__ int cnt[BKT];
    __shared__ int base[BKT];
    __shared__ int pos[BKT];
    const int tid = threadIdx.x;
    const int bid = blockIdx.x;              // r*NBK + b
    const int rr = bid / NBK;
    const int n = min(bcnt_d[bid], CAP);
    int* pp = pairs_d + (size_t)bid * CAP;
    const float* dego = dego_r + (size_t)rr * NN;
    if (tid < BKT) cnt[tid] = 0;
    __syncthreads();
    for (int i = tid; i < n; i += 256) {
        const int p = pp[i];
        stage[i] = p;
        atomicAdd(&cnt[p >> 16], 1);
    }
    __syncthreads();
    if (tid < 64) {
        int carry = 0;
        for (int c0 = 0; c0 < BKT; c0 += 64) {
            const int v = cnt[c0 + tid];
            int incl = v;
            #pragma unroll
            for (int d = 1; d < 64; d <<= 1) {
                const int t = __shfl_up(incl, d, 64);
                if (tid >= d) incl += t;
            }
            base[c0 + tid] = carry + incl - v;
            carry += __shfl(incl, 63, 64);
        }
    }
    __syncthreads();
    if (tid < BKT) {
        pos[tid] = base[tid];
        const int g = (bid % NBK) * BKT + tid;
        if (g < NN) {
            off_g[rr * NN + g] = bid * CAP + base[tid];
            cnt_g[rr * NN + g] = cnt[tid];
            degi_r[rr * NN + g] = rsqrtf((float)max(cnt[tid], 1));
        }
    }
    __syncthreads();
    for (int i = tid; i < n; i += 256) {
        const int p = stage[i];
        const int q = atomicAdd(&pos[p >> 16], 1);
        const int s = p & 0xFFFF;
        pp[q] = s | ((int)f2b(dego[s]) << 16);   // src + folded bf16 weight
    }
}

// ---------------- merged pull (all 3 relations): weighted-CSR bf16 gather + residual ----------------
// (round-9-benched version: 16 lanes/node, unroll-4)
__global__ __launch_bounds__(256) void pull_all_kernel(
    const unsigned short* __restrict__ hb,   // gather table [N,128] bf16
    const unsigned short* __restrict__ xb,   // residual [N,128] bf16
    const int* __restrict__ csrw, const int* __restrict__ off_g,
    const int* __restrict__ cnt_g, const float* __restrict__ degi_r,
    unsigned short* __restrict__ aggb)
{
    const int blk = blockIdx.x;              // r*NPB + nb
    const int r = blk / NPB;
    const int node = (blk % NPB) * 16 + (threadIdx.x >> 4);
    const int lane = threadIdx.x & 15;
    const int gi = r * NN + node;
    const int j0 = off_g[gi];
    const int j1 = j0 + cnt_g[gi];
    const u32x4* hb4 = (const u32x4*)hb;
    float a0 = 0.f, a1 = 0.f, a2 = 0.f, a3 = 0.f, a4 = 0.f, a5 = 0.f, a6 = 0.f, a7 = 0.f;
    int j = j0;
    for (; j + 4 <= j1; j += 4) {
        const unsigned int p0 = csrw[j],     p1 = csrw[j + 1];
        const unsigned int p2 = csrw[j + 2], p3 = csrw[j + 3];
        const float n0 = bhi(p0), n1 = bhi(p1), n2 = bhi(p2), n3 = bhi(p3);
        const u32x4 q0 = hb4[(size_t)(p0 & 0xFFFF) * 16 + lane];
        const u32x4 q1 = hb4[(size_t)(p1 & 0xFFFF) * 16 + lane];
        const u32x4 q2 = hb4[(size_t)(p2 & 0xFFFF) * 16 + lane];
        const u32x4 q3 = hb4[(size_t)(p3 & 0xFFFF) * 16 + lane];
        a0 += blo(q0.x) * n0 + blo(q1.x) * n1 + blo(q2.x) * n2 + blo(q3.x) * n3;
        a1 += bhi(q0.x) * n0 + bhi(q1.x) * n1 + bhi(q2.x) * n2 + bhi(q3.x) * n3;
        a2 += blo(q0.y) * n0 + blo(q1.y) * n1 + blo(q2.y) * n2 + blo(q3.y) * n3;
        a3 += bhi(q0.y) * n0 + bhi(q1.y) * n1 + bhi(q2.y) * n2 + bhi(q3.y) * n3;
        a4 += blo(q0.z) * n0 + blo(q1.z) * n1 + blo(q2.z) * n2 + blo(q3.z) * n3;
        a5 += bhi(q0.z) * n0 + bhi(q1.z) * n1 + bhi(q2.z) * n2 + bhi(q3.z) * n3;
        a6 += blo(q0.w) * n0 + blo(q1.w) * n1 + blo(q2.w) * n2 + blo(q3.w) * n3;
        a7 += bhi(q0.w) * n0 + bhi(q1.w) * n1 + bhi(q2.w) * n2 + bhi(q3.w) * n3;
    }
    for (; j < j1; ++j) {
        const unsigned int p0 = csrw[j];
        const float n0 = bhi(p0);
        const u32x4 q0 = hb4[(size_t)(p0 & 0xFFFF) * 16 + lane];
        a0 += blo(q0.x) * n0; a1 += bhi(q0.x) * n0;
        a2 += blo(q0.y) * n0; a3 += bhi(q0.y) * n0;
        a4 += blo(q0.z) * n0; a5 += bhi(q0.z) * n0;
        a6 += blo(q0.w) * n0; a7 += bhi(q0.w) * n0;
    }
    const float nd = degi_r[gi] * (1.0f - ALPHA_);
    const u32x4 xq = ((const u32x4*)xb)[(size_t)node * 16 + lane];
    u32x4 o;
    o.x = pack2(a0 * nd + ALPHA_ * blo(xq.x), a1 * nd + ALPHA_ * bhi(xq.x));
    o.y = pack2(a2 * nd + ALPHA_ * blo(xq.y), a3 * nd + ALPHA_ * bhi(xq.y));
    o.z = pack2(a4 * nd + ALPHA_ * blo(xq.z), a5 * nd + ALPHA_ * bhi(xq.z));
    o.w = pack2(a6 * nd + ALPHA_ * blo(xq.w), a7 * nd + ALPHA_ * bhi(xq.w));
    ((u32x4*)aggb)[(size_t)gi * 16 + lane] = o;
}

// ---------------- MFMA conv1: rst_r @ W1'_r + b1 -> leaky -> mean over r -> h1b ----------------
template<int LIN>
__global__ __launch_bounds__(256) void conv_mfma_kernel(
    const unsigned short* __restrict__ aggb,   // [R][N][128] bf16
    const unsigned short* __restrict__ WtG,    // [R][128][128] bf16, [n][k]
    const float* __restrict__ bias,            // [R,128]
    unsigned short* __restrict__ houtb)        // h1b
{
    __shared__ unsigned short WtL[DD * 136];   // 34816 B, stride 136 bf16 (17 uint4)
    uint4* WtL4 = (uint4*)WtL;
    const int tid  = threadIdx.x;
    const int wave = tid >> 6;
    const int lane = tid & 63;
    const int l15  = lane & 15;
    const int q    = lane >> 4;                // 0..3
    const int blockRow = blockIdx.x * 64;
    const int row0 = blockRow + wave * 16;
    const int arow = min(row0 + l15, NN - 1);  // A-frag row (clamped)

    f32x4 o[8];
    #pragma unroll
    for (int ct = 0; ct < 8; ++ct) o[ct] = (f32x4){0.f, 0.f, 0.f, 0.f};

    short8 a_cur[4], a_nxt[4];
    {
        const uint4* ap = (const uint4*)aggb + (size_t)arow * 16 + q;
        #pragma unroll
        for (int ks = 0; ks < 4; ++ks)
            a_cur[ks] = __builtin_bit_cast(short8, ap[ks * 4]);
    }

    for (int r = 0; r < RR; ++r) {
        __syncthreads();
        const uint4* wg = (const uint4*)(WtG + (size_t)r * DD * DD);
        for (int i = tid; i < DD * 16; i += 256)
            WtL4[(i >> 4) * 17 + (i & 15)] = wg[i];
        if (r + 1 < RR) {
            const uint4* ap = (const uint4*)aggb + ((size_t)(r + 1) * NN + arow) * 16 + q;
            #pragma unroll
            for (int ks = 0; ks < 4; ++ks)
                a_nxt[ks] = __builtin_bit_cast(short8, ap[ks * 4]);
        }
        __syncthreads();

        #pragma unroll
        for (int ct = 0; ct < 8; ++ct) {
            const float bv = bias[r * DD + ct * 16 + l15];
            f32x4 acc = (f32x4){bv, bv, bv, bv};
            const int nrow = ct * 16 + l15;
            #pragma unroll
            for (int ks = 0; ks < 4; ++ks) {
                const short8 b = __builtin_bit_cast(short8, WtL4[nrow * 17 + ks * 4 + q]);
                acc = __builtin_amdgcn_mfma_f32_16x16x32_bf16(a_cur[ks], b, acc, 0, 0, 0);
            }
            #pragma unroll
            for (int e = 0; e < 4; ++e) {
                float v = acc[e];
                v = v >= 0.f ? v : SLOPE_ * v;
                o[ct][e] += v * (1.0f / 3.0f);
            }
        }
        #pragma unroll
        for (int ks = 0; ks < 4; ++ks) a_cur[ks] = a_nxt[ks];
    }

    __syncthreads();
    unsigned short* tile = WtL;                // rows 0..63, stride 136
    #pragma unroll
    for (int ct = 0; ct < 8; ++ct) {
        const int col = ct * 16 + l15;
        #pragma unroll
        for (int e = 0; e < 4; ++e) {
            const int lrow = wave * 16 + q * 4 + e;
            tile[lrow * 136 + col] = f2b(o[ct][e]);
        }
    }
    __syncthreads();
    for (int i = tid; i < 64 * 16; i += 256) {
        const int lrow = i >> 4, c = i & 15;
        const int grow = blockRow + lrow;
        if (grow < NN)
            ((uint4*)houtb)[(size_t)grow * 16 + c] = WtL4[lrow * 17 + c];
    }
}

// ---------------- pgemm: P_r = h1b @ M_r (r=0..2), Q = ALPHA * x @ sum_r M_r  (all N x 64 bf16) ----
__global__ __launch_bounds__(512) void pgemm_kernel(
    const unsigned short* __restrict__ h1b,  // [N][128] bf16
    const unsigned short* __restrict__ xb,   // [N][128] bf16
    const unsigned short* __restrict__ MT,   // [R][64][128] bf16 (o-major, k inner)
    unsigned short* __restrict__ Pb,         // [R][N][64] bf16
    unsigned short* __restrict__ Qb)         // [N][64] bf16
{
    __shared__ unsigned short MTL[RR * 64 * 136];   // 52224 B, stride 136 (17 uint4)
    uint4* MTL4 = (uint4*)MTL;
    const int tid  = threadIdx.x;
    const int wave = tid >> 6;                 // 0..7
    const int lane = tid & 63;
    const int l15  = lane & 15;
    const int q    = lane >> 4;
    const int blockRow = blockIdx.x * 128;
    const int row0 = blockRow + wave * 16;
    const int arow = min(row0 + l15, NN - 1);

    {   // stage all three M^T matrices (3*64*16 = 3072 uint4)
        const uint4* mg = (const uint4*)MT;
        for (int i = tid; i < RR * 64 * 16; i += 512)
            MTL4[(i >> 4) * 17 + (i & 15)] = mg[i];
    }
    short8 ah[4], ax[4];
    {
        const uint4* hp = (const uint4*)h1b + (size_t)arow * 16 + q;
        const uint4* xp = (const uint4*)xb + (size_t)arow * 16 + q;
        #pragma unroll
        for (int ks = 0; ks < 4; ++ks) {
            ah[ks] = __builtin_bit_cast(short8, hp[ks * 4]);
            ax[ks] = __builtin_bit_cast(short8, xp[ks * 4]);
        }
    }
    __syncthreads();

    // P_r = h1 @ M_r
    for (int r = 0; r < RR; ++r) {
        #pragma unroll
        for (int ct = 0; ct < 4; ++ct) {
            f32x4 acc = (f32x4){0.f, 0.f, 0.f, 0.f};
            const int orow = r * 64 + ct * 16 + l15;
            #pragma unroll
            for (int ks = 0; ks < 4; ++ks) {
                const short8 b = __builtin_bit_cast(short8, MTL4[orow * 17 + ks * 4 + q]);
                acc = __builtin_amdgcn_mfma_f32_16x16x32_bf16(ah[ks], b, acc, 0, 0, 0);
            }
            #pragma unroll
            for (int e = 0; e < 4; ++e) {
                const int grow = row0 + q * 4 + e;
                if (grow < NN)
                    Pb[((size_t)r * NN + grow) * OUTD + ct * 16 + l15] = f2b(acc[e]);
            }
        }
    }
    // Q = ALPHA * x @ (M0+M1+M2)
    #pragma unroll
    for (int ct = 0; ct < 4; ++ct) {
        f32x4 acc = (f32x4){0.f, 0.f, 0.f, 0.f};
        for (int r = 0; r < RR; ++r) {
            const int orow = r * 64 + ct * 16 + l15;
            #pragma unroll
            for (int ks = 0; ks < 4; ++ks) {
                const short8 b = __builtin_bit_cast(short8, MTL4[orow * 17 + ks * 4 + q]);
                acc = __builtin_amdgcn_mfma_f32_16x16x32_bf16(ax[ks], b, acc, 0, 0, 0);
            }
        }
        #pragma unroll
        for (int e = 0; e < 4; ++e) {
            const int grow = row0 + q * 4 + e;
            if (grow < NN)
                Qb[(size_t)grow * OUTD + ct * 16 + l15] = f2b(acc[e] * ALPHA_);
        }
    }
}

// ---------------- pull64: out[v] = sum_r (1-a)*degi_r[v] * gather(P_r) + Q[v] + C ----------------
// (round-9-benched unroll-4 version; 16 lanes/node, 8B/lane, r-loop in registers)
__global__ __launch_bounds__(256) void pull64_kernel(
    const unsigned short* __restrict__ Pb,   // [R][N][64] bf16
    const unsigned short* __restrict__ Qb,   // [N][64] bf16
    const float* __restrict__ Cbuf,          // [64] f32
    const int* __restrict__ csrw, const int* __restrict__ off_g,
    const int* __restrict__ cnt_g, const float* __restrict__ degi_r,
    float* __restrict__ outf)                // [N][64] f32
{
    const int node = blockIdx.x * 16 + (threadIdx.x >> 4);
    const int lane = threadIdx.x & 15;
    const uint2* P2 = (const uint2*)Pb;
    float t0, t1, t2, t3;
    {
        const uint2 qq = ((const uint2*)Qb)[(size_t)node * 16 + lane];
        const float4 cv = ((const float4*)Cbuf)[lane];
        t0 = blo(qq.x) + cv.x; t1 = bhi(qq.x) + cv.y;
        t2 = blo(qq.y) + cv.z; t3 = bhi(qq.y) + cv.w;
    }
    for (int r = 0; r < RR; ++r) {
        const int gi = r * NN + node;
        const int j0 = off_g[gi];
        const int j1 = j0 + cnt_g[gi];
        const uint2* Pr = P2 + (size_t)r * NN * 16;
        float a0 = 0.f, a1 = 0.f, a2 = 0.f, a3 = 0.f;
        int j = j0;
        for (; j + 4 <= j1; j += 4) {
            const unsigned int p0 = csrw[j],     p1 = csrw[j + 1];
            const unsigned int p2 = csrw[j + 2], p3 = csrw[j + 3];
            const float n0 = bhi(p0), n1 = bhi(p1), n2 = bhi(p2), n3 = bhi(p3);
            const uint2 q0 = Pr[(size_t)(p0 & 0xFFFF) * 16 + lane];
            const uint2 q1 = Pr[(size_t)(p1 & 0xFFFF) * 16 + lane];
            const uint2 q2 = Pr[(size_t)(p2 & 0xFFFF) * 16 + lane];
            const uint2 q3 = Pr[(size_t)(p3 & 0xFFFF) * 16 + lane];
            a0 += blo(q0.x) * n0 + blo(q1.x) * n1 + blo(q2.x) * n2 + blo(q3.x) * n3;
            a1 += bhi(q0.x) * n0 + bhi(q1.x) * n1 + bhi(q2.x) * n2 + bhi(q3.x) * n3;
            a2 += blo(q0.y) * n0 + blo(q1.y) * n1 + blo(q2.y) * n2 + blo(q3.y) * n3;
            a3 += bhi(q0.y) * n0 + bhi(q1.y) * n1 + bhi(q2.y) * n2 + bhi(q3.y) * n3;
        }
        for (; j < j1; ++j) {
            const unsigned int p0 = csrw[j];
            const float n0 = bhi(p0);
            const uint2 q0 = Pr[(size_t)(p0 & 0xFFFF) * 16 + lane];
            a0 += blo(q0.x) * n0; a1 += bhi(q0.x) * n0;
            a2 += blo(q0.y) * n0; a3 += bhi(q0.y) * n0;
        }
        const float nd = degi_r[gi] * (1.0f - ALPHA_);
        t0 += a0 * nd; t1 += a1 * nd; t2 += a2 * nd; t3 += a3 * nd;
    }
    float4 ov; ov.x = t0; ov.y = t1; ov.z = t2; ov.w = t3;
    ((float4*)outf)[(size_t)node * 16 + lane] = ov;
}

extern "C" void kernel_launch(void* const* d_in, const int* in_sizes, int n_in,
                              void* d_out, int out_size, void* d_ws, size_t ws_size,
                              hipStream_t stream)
{
    const float* x    = (const float*)d_in[0];
    const int*   src  = (const int*)  d_in[1];
    const int*   dst  = (const int*)  d_in[2];
    const float* W1   = (const float*)d_in[3];
    const float* b1   = (const float*)d_in[4];
    const float* W2   = (const float*)d_in[5];
    const float* b2   = (const float*)d_in[6];
    const float* Wlin = (const float*)d_in[7];
    const float* blin = (const float*)d_in[8];
    float* out = (float*)d_out;

    // ws layout (4B units): bcnt_d[3*NBK] | bcnt_s(layout) | dego_r[3N] | degi_r[3N] |
    //   off_g[3N] | cnt_g[3N] | pad[2] | pairs_d[3*NBK*CAP] | pairs_s(layout u16 region) |
    //   xb | h1b | aggb (aliased by Pb+Qb after conv1) | Wt1 | Wt2 | WlT(layout) | MT | Cbuf
    int*   bcnt_d  = (int*)d_ws;
    int*   bcnt_s  = bcnt_d + RR * NBK;                // layout only
    float* dego_r  = (float*)(bcnt_s + RR * NBK);
    float* degi_r  = dego_r + RR * NN;
    int*   off_g   = (int*)(degi_r + RR * NN);
    int*   cnt_g   = off_g + RR * NN;
    int*   pairs_d = cnt_g + RR * NN + 2;    // +2 -> 16B alignment downstream
    unsigned short* pairs_s = (unsigned short*)(pairs_d + (size_t)RR * NBK * CAP);  // layout only
    unsigned short* xb   = pairs_s + (size_t)RR * NBK * CAPB;
    unsigned short* h1b  = xb + (size_t)NN * DD;
    unsigned short* aggb = h1b + (size_t)NN * DD;
    unsigned short* Wt1  = aggb + (size_t)RR * NN * DD;
    unsigned short* Wt2  = Wt1 + RR * DD * DD;
    unsigned short* WlT  = Wt2 + RR * DD * DD;         // layout only (unused)
    unsigned short* MT   = WlT + OUTD * DD;            // [R][64][128] bf16
    float*          Cbuf = (float*)(MT + RR * DD * OUTD);
    // Pb/Qb alias aggb region (aggb dead after conv1; stream-ordered safe):
    unsigned short* Pb = aggb;                          // RR*NN*64 u16 (9.6M of 19.2M)
    unsigned short* Qb = aggb + (size_t)RR * NN * OUTD; // NN*64 u16

    hipMemsetAsync(bcnt_d, 0, (size_t)RR * NBK * sizeof(int), stream);

    const int gemm_blocks = (NN + 63) / 64;

    // ---- graph preprocessing (split by LDS footprint; same graph both layers) ----
    bin_deg_kernel<<<NBINA + DEGB, 1024, 0, stream>>>(
        src, dst, bcnt_d, pairs_d, dego_r);
    cast_kernel<<<CASTB, 256, 0, stream>>>(
        x, xb, W1, W2, Wlin, Wt1, Wt2, b2, blin, MT, Cbuf);
    sort_kernel<<<RR * NBK, 256, 0, stream>>>(
        pairs_d, bcnt_d, dego_r, off_g, cnt_g, degi_r);

    // ---- conv1: h1b = bf16( mean_r leaky( rst_r @ W1'_r + b1_r ) ) ----
    pull_all_kernel<<<RR * NPB, 256, 0, stream>>>(
        xb, xb, pairs_d, off_g, cnt_g, degi_r, aggb);
    conv_mfma_kernel<0><<<gemm_blocks, 256, 0, stream>>>(
        aggb, Wt1, b1, h1b);

    // ---- layer 2 via associativity: project h1 into 64-dim per relation, THEN gather ----
    pgemm_kernel<<<PGB, 512, 0, stream>>>(h1b, xb, MT, Pb, Qb);
    pull64_kernel<<<P64B, 256, 0, stream>>>(
        Pb, Qb, Cbuf, pairs_d, off_g, cnt_g, degi_r, out);
}

// Round 13
// 396.614 us; speedup vs baseline: 1.5313x; 1.5313x over previous
//
#include <hip/hip_runtime.h>

#define NN    50000
#define DD    128
#define RR    3
#define EE    800000
#define OUTD  64
#define BKT   128                 // nodes per bucket (dst binning)
#define NBK   391                 // ceil(NN/BKT)
#define CAP   2560                // per-bucket edge capacity, 4B dst-entries
#define CAPB  2560                // (layout only)
#define CHUNK 8192                // edges per bin block
#define NCH   98                  // ceil(EE/CHUNK)
#define NBINA (RR * NCH)          // 294 dst-bin blocks
#define DEGB  (RR * 2)            // 6 out-degree histogram blocks (2 per relation, 25K nodes each)
#define DEGN  25000               // nodes per deg block
#define CASTB 6250                // NN*DD/4/256 cast blocks
#define NPB   3125                // NN/16 pull blocks per relation
#define PGB   391                 // ceil(NN/128) pgemm blocks
#define P64B  3125                // NN/16 pull64 blocks
#define ALPHA_ 0.5f
#define SLOPE_ 0.01f
#define BETA1_ 0.6931471805599453f   // log(2)
#define BETA2_ 0.4054651081081644f   // log(1.5)

typedef __attribute__((ext_vector_type(8))) short short8;   // 8 bf16 = 4 VGPRs
typedef __attribute__((ext_vector_type(4))) float f32x4;
typedef __attribute__((ext_vector_type(4))) unsigned int u32x4;

__device__ __forceinline__ unsigned short f2b(float f) {   // fp32 -> bf16 RNE
    unsigned int u = __builtin_bit_cast(unsigned int, f);
    u += 0x7FFFu + ((u >> 16) & 1u);
    return (unsigned short)(u >> 16);
}
__device__ __forceinline__ unsigned int pack2(float lo, float hi) {
    return (unsigned int)f2b(lo) | ((unsigned int)f2b(hi) << 16);
}
__device__ __forceinline__ float blo(unsigned int w) { return __builtin_bit_cast(float, w << 16); }
__device__ __forceinline__ float bhi(unsigned int w) { return __builtin_bit_cast(float, w & 0xFFFF0000u); }

// ---------------- bin+deg: dst-binning | out-degree LDS histogram (50KB union) -------------------
//  [0, NBINA)        : dst-phase LDS bucket-sort (round-6-verified logic, 1024 threads, 39KB)
//  [NBINA, +DEGB)    : out-degree histogram, 2 blocks/relation x 25K nodes packed u16 (50KB).
// Round-12 lesson: the histogram role was a SERIAL latency chain (781 iters x 1 load in flight
// = 280us). Fix: batch 16 independent loads per iteration -> chain 781 -> 49 iterations.
__global__ __launch_bounds__(1024) void bin_deg_kernel(
    const int* __restrict__ src, const int* __restrict__ dst,
    int* __restrict__ bcnt_d, int* __restrict__ pairs_d,
    float* __restrict__ dego_r)
{
    __shared__ unsigned int shmem[12800];    // 51200 B union
    const int tid = threadIdx.x;
    const int blk = blockIdx.x;

    if (blk < NBINA) {
        // ---- dst-phase binning (CHUNK=8192, 1024 threads) ----
        unsigned int* hist    = shmem;               // [NBK]
        unsigned int* lbase   = shmem + NBK;         // [NBK]
        unsigned int* gdelta  = shmem + 2 * NBK;     // [NBK]
        unsigned int* lcur    = shmem + 3 * NBK;     // [NBK]
        unsigned int* staging = shmem + 4 * NBK;     // [CHUNK]
        const int r = blk / NCH;
        const int chunk = blk % NCH;
        const int e0 = chunk * CHUNK;
        const int n = min(CHUNK, EE - e0);
        const int* sp = src + (size_t)r * EE + e0;
        const int* dp = dst + (size_t)r * EE + e0;

        for (int i = tid; i < NBK; i += 1024) hist[i] = 0;
        __syncthreads();
        for (int i = tid; i < n; i += 1024)
            atomicAdd(&hist[dp[i] >> 7], 1u);
        __syncthreads();
        if (tid < 64) {
            int carry = 0;
            for (int c0 = 0; c0 < NBK; c0 += 64) {
                const int idx = c0 + tid;
                const int v = (idx < NBK) ? (int)hist[idx] : 0;
                int incl = v;
                #pragma unroll
                for (int d = 1; d < 64; d <<= 1) {
                    const int t = __shfl_up(incl, d, 64);
                    if (tid >= d) incl += t;
                }
                if (idx < NBK) lbase[idx] = carry + incl - v;
                carry += __shfl(incl, 63, 64);
            }
        }
        __syncthreads();
        for (int b = tid; b < NBK; b += 1024) {
            lcur[b] = lbase[b];
            const int h = (int)hist[b];
            if (h > 0) {
                const int gstart = (r * NBK + b) * CAP + atomicAdd(&bcnt_d[r * NBK + b], h);
                gdelta[b] = (unsigned int)(gstart - (int)lbase[b]);
            }
        }
        __syncthreads();
        for (int i = tid; i < n; i += 1024) {
            const int d = dp[i];
            const int b = d >> 7;
            const int pos = atomicAdd(&lcur[b], 1u);
            staging[pos] = (unsigned int)sp[i] | ((unsigned int)(d & 127) << 16)
                         | ((unsigned int)b << 23);
        }
        __syncthreads();
        for (int j = tid; j < n; j += 1024) {
            const unsigned int v = staging[j];
            const int b = v >> 23;
            const int gi = (int)gdelta[b] + j;
            const int lo = gi - (r * NBK + b) * CAP;
            if (lo < CAP) pairs_d[gi] = (int)(v & 0x7FFFFF);
        }
    } else {
        // ---- out-degree histogram: relation r, node range [base, base+DEGN) ----
        // Batched MLP: 16 independent loads in flight per iteration (round-12 fix).
        const int t = blk - NBINA;               // 0..5
        const int r = t >> 1;
        const int base = (t & 1) * DEGN;
        for (int i = tid; i < DEGN / 2; i += 1024) shmem[i] = 0;
        __syncthreads();
        const int* sp = src + (size_t)r * EE;
        const int nfull = EE / 16384;            // 48 full batches of 16*1024
        for (int it = 0; it < nfull; ++it) {
            const int eb = it * 16384 + tid;
            int vals[16];
            #pragma unroll
            for (int k = 0; k < 16; ++k) vals[k] = sp[eb + k * 1024];
            #pragma unroll
            for (int k = 0; k < 16; ++k) {
                const int s = vals[k] - base;
                if ((unsigned)s < (unsigned)DEGN)
                    atomicAdd(&shmem[s >> 1], 1u << ((s & 1) * 16));
            }
        }
        for (int e = nfull * 16384 + tid; e < EE; e += 1024) {
            const int s = sp[e] - base;
            if ((unsigned)s < (unsigned)DEGN)
                atomicAdd(&shmem[s >> 1], 1u << ((s & 1) * 16));
        }
        __syncthreads();
        for (int g = tid; g < DEGN; g += 1024) {
            const int cnt = (int)((shmem[g >> 1] >> ((g & 1) * 16)) & 0xFFFFu);
            dego_r[r * NN + base + g] = rsqrtf((float)max(cnt, 1));
        }
    }
}

// ---------------- cast: x -> bf16 | W1'/W2' prep | M_r = W2'@Wlin/3 (transposed) | C vector ------
__global__ __launch_bounds__(256) void cast_kernel(
    const float* __restrict__ x, unsigned short* __restrict__ xb,
    const float* __restrict__ W1, const float* __restrict__ W2,
    const float* __restrict__ Wlin, unsigned short* __restrict__ Wt1,
    unsigned short* __restrict__ Wt2,
    const float* __restrict__ b2, const float* __restrict__ blin,
    unsigned short* __restrict__ MT, float* __restrict__ Cbuf)
{
    const int i = blockIdx.x * 256 + threadIdx.x;   // 0 .. NN*DD/4-1
    {
        const float4 v = ((const float4*)x)[i];
        ushort4 o;
        o.x = f2b(v.x); o.y = f2b(v.y); o.z = f2b(v.z); o.w = f2b(v.w);
        ((ushort4*)xb)[i] = o;
    }
    if (i < RR * DD * DD) {
        const int r = i >> 14, rem = i & 16383, nn = rem >> 7, k = rem & 127;
        const float diag = (k == nn) ? 1.0f : 0.0f;
        const float w1 = W1[r * DD * DD + k * DD + nn];
        Wt1[i] = f2b(BETA1_ * w1 + diag * (1.0f - BETA1_));
        const float w2 = W2[r * DD * DD + k * DD + nn];
        Wt2[i] = f2b((BETA2_ * w2 + diag * (1.0f - BETA2_)) * (1.0f / 3.0f));
    }
    if (i < RR * OUTD * DD) {
        // M_r^T[o][k] = ((1-b2)/3)*Wlin[k][o] + (b2/3)*sum_n W2[r][k][n]*Wlin[n][o]
        const int r = i >> 13;
        const int rem = i & 8191;
        const int o = rem >> 7, k = rem & 127;
        float s = 0.f;
        for (int nn = 0; nn < DD; ++nn)
            s += W2[r * DD * DD + k * DD + nn] * Wlin[nn * OUTD + o];
        MT[i] = f2b((BETA2_ / 3.0f) * s + ((1.0f - BETA2_) / 3.0f) * Wlin[k * OUTD + o]);
    }
    if (i < OUTD) {
        float s = blin[i];
        for (int nn = 0; nn < DD; ++nn) {
            const float mb2 = (b2[nn] + b2[DD + nn] + b2[2 * DD + nn]) * (1.0f / 3.0f);
            s += mb2 * Wlin[nn * OUTD + i];
        }
        Cbuf[i] = s;
    }
}

// ---------------- per-bucket counting sort (in place) -> weighted CSR + degi ----------------
__global__ __launch_bounds__(256) void sort_kernel(
    int* __restrict__ pairs_d, const int* __restrict__ bcnt_d,
    const float* __restrict__ dego_r,
    int* __restrict__ off_g, int* __restrict__ cnt_g, float* __restrict__ degi_r)
{
    __shared__ int stage[CAP];
    __shared__ int cnt[BKT];
    __shared__ int base[BKT];
    __shared__ int pos[BKT];
    const int tid = threadIdx.x;
    const int bid = blockIdx.x;              // r*NBK + b
    const int rr = bid / NBK;
    const int n = min(bcnt_d[bid], CAP);
    int* pp = pairs_d + (size_t)bid * CAP;
    const float* dego = dego_r + (size_t)rr * NN;
    if (tid < BKT) cnt[tid] = 0;
    __syncthreads();
    for (int i = tid; i < n; i += 256) {
        const int p = pp[i];
        stage[i] = p;
        atomicAdd(&cnt[p >> 16], 1);
    }
    __syncthreads();
    if (tid < 64) {
        int carry = 0;
        for (int c0 = 0; c0 < BKT; c0 += 64) {
            const int v = cnt[c0 + tid];
            int incl = v;
            #pragma unroll
            for (int d = 1; d < 64; d <<= 1) {
                const int t = __shfl_up(incl, d, 64);
                if (tid >= d) incl += t;
            }
            base[c0 + tid] = carry + incl - v;
            carry += __shfl(incl, 63, 64);
        }
    }
    __syncthreads();
    if (tid < BKT) {
        pos[tid] = base[tid];
        const int g = (bid % NBK) * BKT + tid;
        if (g < NN) {
            off_g[rr * NN + g] = bid * CAP + base[tid];
            cnt_g[rr * NN + g] = cnt[tid];
            degi_r[rr * NN + g] = rsqrtf((float)max(cnt[tid], 1));
        }
    }
    __syncthreads();
    for (int i = tid; i < n; i += 256) {
        const int p = stage[i];
        const int q = atomicAdd(&pos[p >> 16], 1);
        const int s = p & 0xFFFF;
        pp[q] = s | ((int)f2b(dego[s]) << 16);   // src + folded bf16 weight
    }
}

// ---------------- merged pull (all 3 relations): weighted-CSR bf16 gather + residual ----------------
// (round-9-benched version: 16 lanes/node, unroll-4)
__global__ __launch_bounds__(256) void pull_all_kernel(
    const unsigned short* __restrict__ hb,   // gather table [N,128] bf16
    const unsigned short* __restrict__ xb,   // residual [N,128] bf16
    const int* __restrict__ csrw, const int* __restrict__ off_g,
    const int* __restrict__ cnt_g, const float* __restrict__ degi_r,
    unsigned short* __restrict__ aggb)
{
    const int blk = blockIdx.x;              // r*NPB + nb
    const int r = blk / NPB;
    const int node = (blk % NPB) * 16 + (threadIdx.x >> 4);
    const int lane = threadIdx.x & 15;
    const int gi = r * NN + node;
    const int j0 = off_g[gi];
    const int j1 = j0 + cnt_g[gi];
    const u32x4* hb4 = (const u32x4*)hb;
    float a0 = 0.f, a1 = 0.f, a2 = 0.f, a3 = 0.f, a4 = 0.f, a5 = 0.f, a6 = 0.f, a7 = 0.f;
    int j = j0;
    for (; j + 4 <= j1; j += 4) {
        const unsigned int p0 = csrw[j],     p1 = csrw[j + 1];
        const unsigned int p2 = csrw[j + 2], p3 = csrw[j + 3];
        const float n0 = bhi(p0), n1 = bhi(p1), n2 = bhi(p2), n3 = bhi(p3);
        const u32x4 q0 = hb4[(size_t)(p0 & 0xFFFF) * 16 + lane];
        const u32x4 q1 = hb4[(size_t)(p1 & 0xFFFF) * 16 + lane];
        const u32x4 q2 = hb4[(size_t)(p2 & 0xFFFF) * 16 + lane];
        const u32x4 q3 = hb4[(size_t)(p3 & 0xFFFF) * 16 + lane];
        a0 += blo(q0.x) * n0 + blo(q1.x) * n1 + blo(q2.x) * n2 + blo(q3.x) * n3;
        a1 += bhi(q0.x) * n0 + bhi(q1.x) * n1 + bhi(q2.x) * n2 + bhi(q3.x) * n3;
        a2 += blo(q0.y) * n0 + blo(q1.y) * n1 + blo(q2.y) * n2 + blo(q3.y) * n3;
        a3 += bhi(q0.y) * n0 + bhi(q1.y) * n1 + bhi(q2.y) * n2 + bhi(q3.y) * n3;
        a4 += blo(q0.z) * n0 + blo(q1.z) * n1 + blo(q2.z) * n2 + blo(q3.z) * n3;
        a5 += bhi(q0.z) * n0 + bhi(q1.z) * n1 + bhi(q2.z) * n2 + bhi(q3.z) * n3;
        a6 += blo(q0.w) * n0 + blo(q1.w) * n1 + blo(q2.w) * n2 + blo(q3.w) * n3;
        a7 += bhi(q0.w) * n0 + bhi(q1.w) * n1 + bhi(q2.w) * n2 + bhi(q3.w) * n3;
    }
    for (; j < j1; ++j) {
        const unsigned int p0 = csrw[j];
        const float n0 = bhi(p0);
        const u32x4 q0 = hb4[(size_t)(p0 & 0xFFFF) * 16 + lane];
        a0 += blo(q0.x) * n0; a1 += bhi(q0.x) * n0;
        a2 += blo(q0.y) * n0; a3 += bhi(q0.y) * n0;
        a4 += blo(q0.z) * n0; a5 += bhi(q0.z) * n0;
        a6 += blo(q0.w) * n0; a7 += bhi(q0.w) * n0;
    }
    const float nd = degi_r[gi] * (1.0f - ALPHA_);
    const u32x4 xq = ((const u32x4*)xb)[(size_t)node * 16 + lane];
    u32x4 o;
    o.x = pack2(a0 * nd + ALPHA_ * blo(xq.x), a1 * nd + ALPHA_ * bhi(xq.x));
    o.y = pack2(a2 * nd + ALPHA_ * blo(xq.y), a3 * nd + ALPHA_ * bhi(xq.y));
    o.z = pack2(a4 * nd + ALPHA_ * blo(xq.z), a5 * nd + ALPHA_ * bhi(xq.z));
    o.w = pack2(a6 * nd + ALPHA_ * blo(xq.w), a7 * nd + ALPHA_ * bhi(xq.w));
    ((u32x4*)aggb)[(size_t)gi * 16 + lane] = o;
}

// ---------------- MFMA conv1: rst_r @ W1'_r + b1 -> leaky -> mean over r -> h1b ----------------
template<int LIN>
__global__ __launch_bounds__(256) void conv_mfma_kernel(
    const unsigned short* __restrict__ aggb,   // [R][N][128] bf16
    const unsigned short* __restrict__ WtG,    // [R][128][128] bf16, [n][k]
    const float* __restrict__ bias,            // [R,128]
    unsigned short* __restrict__ houtb)        // h1b
{
    __shared__ unsigned short WtL[DD * 136];   // 34816 B, stride 136 bf16 (17 uint4)
    uint4* WtL4 = (uint4*)WtL;
    const int tid  = threadIdx.x;
    const int wave = tid >> 6;
    const int lane = tid & 63;
    const int l15  = lane & 15;
    const int q    = lane >> 4;                // 0..3
    const int blockRow = blockIdx.x * 64;
    const int row0 = blockRow + wave * 16;
    const int arow = min(row0 + l15, NN - 1);  // A-frag row (clamped)

    f32x4 o[8];
    #pragma unroll
    for (int ct = 0; ct < 8; ++ct) o[ct] = (f32x4){0.f, 0.f, 0.f, 0.f};

    short8 a_cur[4], a_nxt[4];
    {
        const uint4* ap = (const uint4*)aggb + (size_t)arow * 16 + q;
        #pragma unroll
        for (int ks = 0; ks < 4; ++ks)
            a_cur[ks] = __builtin_bit_cast(short8, ap[ks * 4]);
    }

    for (int r = 0; r < RR; ++r) {
        __syncthreads();
        const uint4* wg = (const uint4*)(WtG + (size_t)r * DD * DD);
        for (int i = tid; i < DD * 16; i += 256)
            WtL4[(i >> 4) * 17 + (i & 15)] = wg[i];
        if (r + 1 < RR) {
            const uint4* ap = (const uint4*)aggb + ((size_t)(r + 1) * NN + arow) * 16 + q;
            #pragma unroll
            for (int ks = 0; ks < 4; ++ks)
                a_nxt[ks] = __builtin_bit_cast(short8, ap[ks * 4]);
        }
        __syncthreads();

        #pragma unroll
        for (int ct = 0; ct < 8; ++ct) {
            const float bv = bias[r * DD + ct * 16 + l15];
            f32x4 acc = (f32x4){bv, bv, bv, bv};
            const int nrow = ct * 16 + l15;
            #pragma unroll
            for (int ks = 0; ks < 4; ++ks) {
                const short8 b = __builtin_bit_cast(short8, WtL4[nrow * 17 + ks * 4 + q]);
                acc = __builtin_amdgcn_mfma_f32_16x16x32_bf16(a_cur[ks], b, acc, 0, 0, 0);
            }
            #pragma unroll
            for (int e = 0; e < 4; ++e) {
                float v = acc[e];
                v = v >= 0.f ? v : SLOPE_ * v;
                o[ct][e] += v * (1.0f / 3.0f);
            }
        }
        #pragma unroll
        for (int ks = 0; ks < 4; ++ks) a_cur[ks] = a_nxt[ks];
    }

    __syncthreads();
    unsigned short* tile = WtL;                // rows 0..63, stride 136
    #pragma unroll
    for (int ct = 0; ct < 8; ++ct) {
        const int col = ct * 16 + l15;
        #pragma unroll
        for (int e = 0; e < 4; ++e) {
            const int lrow = wave * 16 + q * 4 + e;
            tile[lrow * 136 + col] = f2b(o[ct][e]);
        }
    }
    __syncthreads();
    for (int i = tid; i < 64 * 16; i += 256) {
        const int lrow = i >> 4, c = i & 15;
        const int grow = blockRow + lrow;
        if (grow < NN)
            ((uint4*)houtb)[(size_t)grow * 16 + c] = WtL4[lrow * 17 + c];
    }
}

// ---------------- pgemm: P_r = h1b @ M_r (r=0..2), Q = ALPHA * x @ sum_r M_r  (all N x 64 bf16) ----
__global__ __launch_bounds__(512) void pgemm_kernel(
    const unsigned short* __restrict__ h1b,  // [N][128] bf16
    const unsigned short* __restrict__ xb,   // [N][128] bf16
    const unsigned short* __restrict__ MT,   // [R][64][128] bf16 (o-major, k inner)
    unsigned short* __restrict__ Pb,         // [R][N][64] bf16
    unsigned short* __restrict__ Qb)         // [N][64] bf16
{
    __shared__ unsigned short MTL[RR * 64 * 136];   // 52224 B, stride 136 (17 uint4)
    uint4* MTL4 = (uint4*)MTL;
    const int tid  = threadIdx.x;
    const int wave = tid >> 6;                 // 0..7
    const int lane = tid & 63;
    const int l15  = lane & 15;
    const int q    = lane >> 4;
    const int blockRow = blockIdx.x * 128;
    const int row0 = blockRow + wave * 16;
    const int arow = min(row0 + l15, NN - 1);

    {   // stage all three M^T matrices (3*64*16 = 3072 uint4)
        const uint4* mg = (const uint4*)MT;
        for (int i = tid; i < RR * 64 * 16; i += 512)
            MTL4[(i >> 4) * 17 + (i & 15)] = mg[i];
    }
    short8 ah[4], ax[4];
    {
        const uint4* hp = (const uint4*)h1b + (size_t)arow * 16 + q;
        const uint4* xp = (const uint4*)xb + (size_t)arow * 16 + q;
        #pragma unroll
        for (int ks = 0; ks < 4; ++ks) {
            ah[ks] = __builtin_bit_cast(short8, hp[ks * 4]);
            ax[ks] = __builtin_bit_cast(short8, xp[ks * 4]);
        }
    }
    __syncthreads();

    // P_r = h1 @ M_r
    for (int r = 0; r < RR; ++r) {
        #pragma unroll
        for (int ct = 0; ct < 4; ++ct) {
            f32x4 acc = (f32x4){0.f, 0.f, 0.f, 0.f};
            const int orow = r * 64 + ct * 16 + l15;
            #pragma unroll
            for (int ks = 0; ks < 4; ++ks) {
                const short8 b = __builtin_bit_cast(short8, MTL4[orow * 17 + ks * 4 + q]);
                acc = __builtin_amdgcn_mfma_f32_16x16x32_bf16(ah[ks], b, acc, 0, 0, 0);
            }
            #pragma unroll
            for (int e = 0; e < 4; ++e) {
                const int grow = row0 + q * 4 + e;
                if (grow < NN)
                    Pb[((size_t)r * NN + grow) * OUTD + ct * 16 + l15] = f2b(acc[e]);
            }
        }
    }
    // Q = ALPHA * x @ (M0+M1+M2)
    #pragma unroll
    for (int ct = 0; ct < 4; ++ct) {
        f32x4 acc = (f32x4){0.f, 0.f, 0.f, 0.f};
        for (int r = 0; r < RR; ++r) {
            const int orow = r * 64 + ct * 16 + l15;
            #pragma unroll
            for (int ks = 0; ks < 4; ++ks) {
                const short8 b = __builtin_bit_cast(short8, MTL4[orow * 17 + ks * 4 + q]);
                acc = __builtin_amdgcn_mfma_f32_16x16x32_bf16(ax[ks], b, acc, 0, 0, 0);
            }
        }
        #pragma unroll
        for (int e = 0; e < 4; ++e) {
            const int grow = row0 + q * 4 + e;
            if (grow < NN)
                Qb[(size_t)grow * OUTD + ct * 16 + l15] = f2b(acc[e] * ALPHA_);
        }
    }
}

// ---------------- pull64: out[v] = sum_r (1-a)*degi_r[v] * gather(P_r) + Q[v] + C ----------------
// (round-9-benched unroll-4 version; 16 lanes/node, 8B/lane, r-loop in registers)
__global__ __launch_bounds__(256) void pull64_kernel(
    const unsigned short* __restrict__ Pb,   // [R][N][64] bf16
    const unsigned short* __restrict__ Qb,   // [N][64] bf16
    const float* __restrict__ Cbuf,          // [64] f32
    const int* __restrict__ csrw, const int* __restrict__ off_g,
    const int* __restrict__ cnt_g, const float* __restrict__ degi_r,
    float* __restrict__ outf)                // [N][64] f32
{
    const int node = blockIdx.x * 16 + (threadIdx.x >> 4);
    const int lane = threadIdx.x & 15;
    const uint2* P2 = (const uint2*)Pb;
    float t0, t1, t2, t3;
    {
        const uint2 qq = ((const uint2*)Qb)[(size_t)node * 16 + lane];
        const float4 cv = ((const float4*)Cbuf)[lane];
        t0 = blo(qq.x) + cv.x; t1 = bhi(qq.x) + cv.y;
        t2 = blo(qq.y) + cv.z; t3 = bhi(qq.y) + cv.w;
    }
    for (int r = 0; r < RR; ++r) {
        const int gi = r * NN + node;
        const int j0 = off_g[gi];
        const int j1 = j0 + cnt_g[gi];
        const uint2* Pr = P2 + (size_t)r * NN * 16;
        float a0 = 0.f, a1 = 0.f, a2 = 0.f, a3 = 0.f;
        int j = j0;
        for (; j + 4 <= j1; j += 4) {
            const unsigned int p0 = csrw[j],     p1 = csrw[j + 1];
            const unsigned int p2 = csrw[j + 2], p3 = csrw[j + 3];
            const float n0 = bhi(p0), n1 = bhi(p1), n2 = bhi(p2), n3 = bhi(p3);
            const uint2 q0 = Pr[(size_t)(p0 & 0xFFFF) * 16 + lane];
            const uint2 q1 = Pr[(size_t)(p1 & 0xFFFF) * 16 + lane];
            const uint2 q2 = Pr[(size_t)(p2 & 0xFFFF) * 16 + lane];
            const uint2 q3 = Pr[(size_t)(p3 & 0xFFFF) * 16 + lane];
            a0 += blo(q0.x) * n0 + blo(q1.x) * n1 + blo(q2.x) * n2 + blo(q3.x) * n3;
            a1 += bhi(q0.x) * n0 + bhi(q1.x) * n1 + bhi(q2.x) * n2 + bhi(q3.x) * n3;
            a2 += blo(q0.y) * n0 + blo(q1.y) * n1 + blo(q2.y) * n2 + blo(q3.y) * n3;
            a3 += bhi(q0.y) * n0 + bhi(q1.y) * n1 + bhi(q2.y) * n2 + bhi(q3.y) * n3;
        }
        for (; j < j1; ++j) {
            const unsigned int p0 = csrw[j];
            const float n0 = bhi(p0);
            const uint2 q0 = Pr[(size_t)(p0 & 0xFFFF) * 16 + lane];
            a0 += blo(q0.x) * n0; a1 += bhi(q0.x) * n0;
            a2 += blo(q0.y) * n0; a3 += bhi(q0.y) * n0;
        }
        const float nd = degi_r[gi] * (1.0f - ALPHA_);
        t0 += a0 * nd; t1 += a1 * nd; t2 += a2 * nd; t3 += a3 * nd;
    }
    float4 ov; ov.x = t0; ov.y = t1; ov.z = t2; ov.w = t3;
    ((float4*)outf)[(size_t)node * 16 + lane] = ov;
}

extern "C" void kernel_launch(void* const* d_in, const int* in_sizes, int n_in,
                              void* d_out, int out_size, void* d_ws, size_t ws_size,
                              hipStream_t stream)
{
    const float* x    = (const float*)d_in[0];
    const int*   src  = (const int*)  d_in[1];
    const int*   dst  = (const int*)  d_in[2];
    const float* W1   = (const float*)d_in[3];
    const float* b1   = (const float*)d_in[4];
    const float* W2   = (const float*)d_in[5];
    const float* b2   = (const float*)d_in[6];
    const float* Wlin = (const float*)d_in[7];
    const float* blin = (const float*)d_in[8];
    float* out = (float*)d_out;

    // ws layout (4B units): bcnt_d[3*NBK] | bcnt_s(layout) | dego_r[3N] | degi_r[3N] |
    //   off_g[3N] | cnt_g[3N] | pad[2] | pairs_d[3*NBK*CAP] | pairs_s(layout u16 region) |
    //   xb | h1b | aggb (aliased by Pb+Qb after conv1) | Wt1 | Wt2 | WlT(layout) | MT | Cbuf
    int*   bcnt_d  = (int*)d_ws;
    int*   bcnt_s  = bcnt_d + RR * NBK;                // layout only
    float* dego_r  = (float*)(bcnt_s + RR * NBK);
    float* degi_r  = dego_r + RR * NN;
    int*   off_g   = (int*)(degi_r + RR * NN);
    int*   cnt_g   = off_g + RR * NN;
    int*   pairs_d = cnt_g + RR * NN + 2;    // +2 -> 16B alignment downstream
    unsigned short* pairs_s = (unsigned short*)(pairs_d + (size_t)RR * NBK * CAP);  // layout only
    unsigned short* xb   = pairs_s + (size_t)RR * NBK * CAPB;
    unsigned short* h1b  = xb + (size_t)NN * DD;
    unsigned short* aggb = h1b + (size_t)NN * DD;
    unsigned short* Wt1  = aggb + (size_t)RR * NN * DD;
    unsigned short* Wt2  = Wt1 + RR * DD * DD;
    unsigned short* WlT  = Wt2 + RR * DD * DD;         // layout only (unused)
    unsigned short* MT   = WlT + OUTD * DD;            // [R][64][128] bf16
    float*          Cbuf = (float*)(MT + RR * DD * OUTD);
    // Pb/Qb alias aggb region (aggb dead after conv1; stream-ordered safe):
    unsigned short* Pb = aggb;                          // RR*NN*64 u16 (9.6M of 19.2M)
    unsigned short* Qb = aggb + (size_t)RR * NN * OUTD; // NN*64 u16

    hipMemsetAsync(bcnt_d, 0, (size_t)RR * NBK * sizeof(int), stream);

    const int gemm_blocks = (NN + 63) / 64;

    // ---- graph preprocessing (split by LDS footprint; same graph both layers) ----
    bin_deg_kernel<<<NBINA + DEGB, 1024, 0, stream>>>(
        src, dst, bcnt_d, pairs_d, dego_r);
    cast_kernel<<<CASTB, 256, 0, stream>>>(
        x, xb, W1, W2, Wlin, Wt1, Wt2, b2, blin, MT, Cbuf);
    sort_kernel<<<RR * NBK, 256, 0, stream>>>(
        pairs_d, bcnt_d, dego_r, off_g, cnt_g, degi_r);

    // ---- conv1: h1b = bf16( mean_r leaky( rst_r @ W1'_r + b1_r ) ) ----
    pull_all_kernel<<<RR * NPB, 256, 0, stream>>>(
        xb, xb, pairs_d, off_g, cnt_g, degi_r, aggb);
    conv_mfma_kernel<0><<<gemm_blocks, 256, 0, stream>>>(
        aggb, Wt1, b1, h1b);

    // ---- layer 2 via associativity: project h1 into 64-dim per relation, THEN gather ----
    pgemm_kernel<<<PGB, 512, 0, stream>>>(h1b, xb, MT, Pb, Qb);
    pull64_kernel<<<P64B, 256, 0, stream>>>(
        Pb, Qb, Cbuf, pairs_d, off_g, cnt_g, degi_r, out);
}

// Round 14
// 382.239 us; speedup vs baseline: 1.5889x; 1.0376x over previous
//
#include <hip/hip_runtime.h>

#define NN    50000
#define DD    128
#define RR    3
#define EE    800000
#define OUTD  64
#define BKT   128                 // nodes per bucket (dst binning)
#define NBK   391                 // ceil(NN/BKT)
#define CAP   2560                // per-bucket edge capacity, 4B dst-entries
#define CAPB  2560                // (layout only)
#define CHUNK 8192                // edges per bin block
#define NCH   98                  // ceil(EE/CHUNK)
#define NBINA (RR * NCH)          // 294 dst-bin blocks
#define DEGB  (RR * 2)            // 6 out-degree histogram blocks (2 per relation, 25K nodes each)
#define DEGN  25000               // nodes per deg block
#define CASTB 1563                // ceil(NN*DD/4 / 1024) cast blocks (1024-thr role)
#define NPB   3125                // NN/16 pull blocks per relation
#define PGB   391                 // ceil(NN/128) pgemm blocks
#define P64B  3125                // NN/16 pull64 blocks
#define ALPHA_ 0.5f
#define SLOPE_ 0.01f
#define BETA1_ 0.6931471805599453f   // log(2)
#define BETA2_ 0.4054651081081644f   // log(1.5)

typedef __attribute__((ext_vector_type(8))) short short8;   // 8 bf16 = 4 VGPRs
typedef __attribute__((ext_vector_type(4))) float f32x4;
typedef __attribute__((ext_vector_type(4))) unsigned int u32x4;

__device__ __forceinline__ unsigned short f2b(float f) {   // fp32 -> bf16 RNE
    unsigned int u = __builtin_bit_cast(unsigned int, f);
    u += 0x7FFFu + ((u >> 16) & 1u);
    return (unsigned short)(u >> 16);
}
__device__ __forceinline__ unsigned int pack2(float lo, float hi) {
    return (unsigned int)f2b(lo) | ((unsigned int)f2b(hi) << 16);
}
__device__ __forceinline__ float blo(unsigned int w) { return __builtin_bit_cast(float, w << 16); }
__device__ __forceinline__ float bhi(unsigned int w) { return __builtin_bit_cast(float, w & 0xFFFF0000u); }

// ---------------- merged prep: dst-binning | out-degree histogram | cast + W/M/C ----------------
// ONE launch (round-13 lesson: separate launches serialize; round-9's merged prep overlapped).
// 50KB LDS union -> 2 blocks/CU x 1024 thr = full thread occupancy for ALL roles (round-11's
// failure was a 100KB role; 50KB costs nothing).
//  [0, NBINA)          : dst-phase LDS bucket-sort (R13-verified @1024 thr, 39KB)
//  [NBINA, +DEGB)      : out-degree histogram, batch-16 MLP (R13-verified), 50KB packed u16
//  [NBINA+DEGB, +CASTB): x cast + W1'/W2' + M_r = W2'@Wlin/3 + C (R9/R13-verified content)
__global__ __launch_bounds__(1024) void prep_kernel(
    const int* __restrict__ src, const int* __restrict__ dst,
    int* __restrict__ bcnt_d, int* __restrict__ pairs_d,
    float* __restrict__ dego_r,
    const float* __restrict__ x, unsigned short* __restrict__ xb,
    const float* __restrict__ W1, const float* __restrict__ W2,
    const float* __restrict__ Wlin, unsigned short* __restrict__ Wt1,
    unsigned short* __restrict__ Wt2,
    const float* __restrict__ b2, const float* __restrict__ blin,
    unsigned short* __restrict__ MT, float* __restrict__ Cbuf)
{
    __shared__ unsigned int shmem[12800];    // 51200 B union
    const int tid = threadIdx.x;
    const int blk = blockIdx.x;

    if (blk < NBINA) {
        // ---- dst-phase binning (CHUNK=8192, 1024 threads) ----
        unsigned int* hist    = shmem;               // [NBK]
        unsigned int* lbase   = shmem + NBK;         // [NBK]
        unsigned int* gdelta  = shmem + 2 * NBK;     // [NBK]
        unsigned int* lcur    = shmem + 3 * NBK;     // [NBK]
        unsigned int* staging = shmem + 4 * NBK;     // [CHUNK]
        const int r = blk / NCH;
        const int chunk = blk % NCH;
        const int e0 = chunk * CHUNK;
        const int n = min(CHUNK, EE - e0);
        const int* sp = src + (size_t)r * EE + e0;
        const int* dp = dst + (size_t)r * EE + e0;

        for (int i = tid; i < NBK; i += 1024) hist[i] = 0;
        __syncthreads();
        for (int i = tid; i < n; i += 1024)
            atomicAdd(&hist[dp[i] >> 7], 1u);
        __syncthreads();
        if (tid < 64) {
            int carry = 0;
            for (int c0 = 0; c0 < NBK; c0 += 64) {
                const int idx = c0 + tid;
                const int v = (idx < NBK) ? (int)hist[idx] : 0;
                int incl = v;
                #pragma unroll
                for (int d = 1; d < 64; d <<= 1) {
                    const int t = __shfl_up(incl, d, 64);
                    if (tid >= d) incl += t;
                }
                if (idx < NBK) lbase[idx] = carry + incl - v;
                carry += __shfl(incl, 63, 64);
            }
        }
        __syncthreads();
        for (int b = tid; b < NBK; b += 1024) {
            lcur[b] = lbase[b];
            const int h = (int)hist[b];
            if (h > 0) {
                const int gstart = (r * NBK + b) * CAP + atomicAdd(&bcnt_d[r * NBK + b], h);
                gdelta[b] = (unsigned int)(gstart - (int)lbase[b]);
            }
        }
        __syncthreads();
        for (int i = tid; i < n; i += 1024) {
            const int d = dp[i];
            const int b = d >> 7;
            const int pos = atomicAdd(&lcur[b], 1u);
            staging[pos] = (unsigned int)sp[i] | ((unsigned int)(d & 127) << 16)
                         | ((unsigned int)b << 23);
        }
        __syncthreads();
        for (int j = tid; j < n; j += 1024) {
            const unsigned int v = staging[j];
            const int b = v >> 23;
            const int gi = (int)gdelta[b] + j;
            const int lo = gi - (r * NBK + b) * CAP;
            if (lo < CAP) pairs_d[gi] = (int)(v & 0x7FFFFF);
        }
    } else if (blk < NBINA + DEGB) {
        // ---- out-degree histogram: relation r, node range [base, base+DEGN); batch-16 MLP ----
        const int t = blk - NBINA;               // 0..5
        const int r = t >> 1;
        const int base = (t & 1) * DEGN;
        for (int i = tid; i < DEGN / 2; i += 1024) shmem[i] = 0;
        __syncthreads();
        const int* sp = src + (size_t)r * EE;
        const int nfull = EE / 16384;            // 48 full batches of 16*1024
        for (int it = 0; it < nfull; ++it) {
            const int eb = it * 16384 + tid;
            int vals[16];
            #pragma unroll
            for (int k = 0; k < 16; ++k) vals[k] = sp[eb + k * 1024];
            #pragma unroll
            for (int k = 0; k < 16; ++k) {
                const int s = vals[k] - base;
                if ((unsigned)s < (unsigned)DEGN)
                    atomicAdd(&shmem[s >> 1], 1u << ((s & 1) * 16));
            }
        }
        for (int e = nfull * 16384 + tid; e < EE; e += 1024) {
            const int s = sp[e] - base;
            if ((unsigned)s < (unsigned)DEGN)
                atomicAdd(&shmem[s >> 1], 1u << ((s & 1) * 16));
        }
        __syncthreads();
        for (int g = tid; g < DEGN; g += 1024) {
            const int cnt = (int)((shmem[g >> 1] >> ((g & 1) * 16)) & 0xFFFFu);
            dego_r[r * NN + base + g] = rsqrtf((float)max(cnt, 1));
        }
    } else {
        // ---- x cast + W1'/W2' prep + M/C prep (1024-thread streaming role) ----
        const int i = (blk - NBINA - DEGB) * 1024 + tid;   // 0 .. NN*DD/4-1 (+pad)
        if (i < NN * DD / 4) {
            const float4 v = ((const float4*)x)[i];
            ushort4 o;
            o.x = f2b(v.x); o.y = f2b(v.y); o.z = f2b(v.z); o.w = f2b(v.w);
            ((ushort4*)xb)[i] = o;
        }
        if (i < RR * DD * DD) {
            const int r = i >> 14, rem = i & 16383, nn = rem >> 7, k = rem & 127;
            const float diag = (k == nn) ? 1.0f : 0.0f;
            const float w1 = W1[r * DD * DD + k * DD + nn];
            Wt1[i] = f2b(BETA1_ * w1 + diag * (1.0f - BETA1_));
            const float w2 = W2[r * DD * DD + k * DD + nn];
            Wt2[i] = f2b((BETA2_ * w2 + diag * (1.0f - BETA2_)) * (1.0f / 3.0f));
        }
        if (i < RR * OUTD * DD) {
            // M_r^T[o][k] = ((1-b2)/3)*Wlin[k][o] + (b2/3)*sum_n W2[r][k][n]*Wlin[n][o]
            const int r = i >> 13;
            const int rem = i & 8191;
            const int o = rem >> 7, k = rem & 127;
            float s = 0.f;
            for (int nn = 0; nn < DD; ++nn)
                s += W2[r * DD * DD + k * DD + nn] * Wlin[nn * OUTD + o];
            MT[i] = f2b((BETA2_ / 3.0f) * s + ((1.0f - BETA2_) / 3.0f) * Wlin[k * OUTD + o]);
        }
        if (i < OUTD) {
            float s = blin[i];
            for (int nn = 0; nn < DD; ++nn) {
                const float mb2 = (b2[nn] + b2[DD + nn] + b2[2 * DD + nn]) * (1.0f / 3.0f);
                s += mb2 * Wlin[nn * OUTD + i];
            }
            Cbuf[i] = s;
        }
    }
}

// ---------------- per-bucket counting sort (in place) -> weighted CSR + degi ----------------
__global__ __launch_bounds__(256) void sort_kernel(
    int* __restrict__ pairs_d, const int* __restrict__ bcnt_d,
    const float* __restrict__ dego_r,
    int* __restrict__ off_g, int* __restrict__ cnt_g, float* __restrict__ degi_r)
{
    __shared__ int stage[CAP];
    __shared__ int cnt[BKT];
    __shared__ int base[BKT];
    __shared__ int pos[BKT];
    const int tid = threadIdx.x;
    const int bid = blockIdx.x;              // r*NBK + b
    const int rr = bid / NBK;
    const int n = min(bcnt_d[bid], CAP);
    int* pp = pairs_d + (size_t)bid * CAP;
    const float* dego = dego_r + (size_t)rr * NN;
    if (tid < BKT) cnt[tid] = 0;
    __syncthreads();
    for (int i = tid; i < n; i += 256) {
        const int p = pp[i];
        stage[i] = p;
        atomicAdd(&cnt[p >> 16], 1);
    }
    __syncthreads();
    if (tid < 64) {
        int carry = 0;
        for (int c0 = 0; c0 < BKT; c0 += 64) {
            const int v = cnt[c0 + tid];
            int incl = v;
            #pragma unroll
            for (int d = 1; d < 64; d <<= 1) {
                const int t = __shfl_up(incl, d, 64);
                if (tid >= d) incl += t;
            }
            base[c0 + tid] = carry + incl - v;
            carry += __shfl(incl, 63, 64);
        }
    }
    __syncthreads();
    if (tid < BKT) {
        pos[tid] = base[tid];
        const int g = (bid % NBK) * BKT + tid;
        if (g < NN) {
            off_g[rr * NN + g] = bid * CAP + base[tid];
            cnt_g[rr * NN + g] = cnt[tid];
            degi_r[rr * NN + g] = rsqrtf((float)max(cnt[tid], 1));
        }
    }
    __syncthreads();
    for (int i = tid; i < n; i += 256) {
        const int p = stage[i];
        const int q = atomicAdd(&pos[p >> 16], 1);
        const int s = p & 0xFFFF;
        pp[q] = s | ((int)f2b(dego[s]) << 16);   // src + folded bf16 weight
    }
}

// ---------------- merged pull (all 3 relations): weighted-CSR bf16 gather + residual ----------------
// (round-9-benched version: 16 lanes/node, unroll-4)
__global__ __launch_bounds__(256) void pull_all_kernel(
    const unsigned short* __restrict__ hb,   // gather table [N,128] bf16
    const unsigned short* __restrict__ xb,   // residual [N,128] bf16
    const int* __restrict__ csrw, const int* __restrict__ off_g,
    const int* __restrict__ cnt_g, const float* __restrict__ degi_r,
    unsigned short* __restrict__ aggb)
{
    const int blk = blockIdx.x;              // r*NPB + nb
    const int r = blk / NPB;
    const int node = (blk % NPB) * 16 + (threadIdx.x >> 4);
    const int lane = threadIdx.x & 15;
    const int gi = r * NN + node;
    const int j0 = off_g[gi];
    const int j1 = j0 + cnt_g[gi];
    const u32x4* hb4 = (const u32x4*)hb;
    float a0 = 0.f, a1 = 0.f, a2 = 0.f, a3 = 0.f, a4 = 0.f, a5 = 0.f, a6 = 0.f, a7 = 0.f;
    int j = j0;
    for (; j + 4 <= j1; j += 4) {
        const unsigned int p0 = csrw[j],     p1 = csrw[j + 1];
        const unsigned int p2 = csrw[j + 2], p3 = csrw[j + 3];
        const float n0 = bhi(p0), n1 = bhi(p1), n2 = bhi(p2), n3 = bhi(p3);
        const u32x4 q0 = hb4[(size_t)(p0 & 0xFFFF) * 16 + lane];
        const u32x4 q1 = hb4[(size_t)(p1 & 0xFFFF) * 16 + lane];
        const u32x4 q2 = hb4[(size_t)(p2 & 0xFFFF) * 16 + lane];
        const u32x4 q3 = hb4[(size_t)(p3 & 0xFFFF) * 16 + lane];
        a0 += blo(q0.x) * n0 + blo(q1.x) * n1 + blo(q2.x) * n2 + blo(q3.x) * n3;
        a1 += bhi(q0.x) * n0 + bhi(q1.x) * n1 + bhi(q2.x) * n2 + bhi(q3.x) * n3;
        a2 += blo(q0.y) * n0 + blo(q1.y) * n1 + blo(q2.y) * n2 + blo(q3.y) * n3;
        a3 += bhi(q0.y) * n0 + bhi(q1.y) * n1 + bhi(q2.y) * n2 + bhi(q3.y) * n3;
        a4 += blo(q0.z) * n0 + blo(q1.z) * n1 + blo(q2.z) * n2 + blo(q3.z) * n3;
        a5 += bhi(q0.z) * n0 + bhi(q1.z) * n1 + bhi(q2.z) * n2 + bhi(q3.z) * n3;
        a6 += blo(q0.w) * n0 + blo(q1.w) * n1 + blo(q2.w) * n2 + blo(q3.w) * n3;
        a7 += bhi(q0.w) * n0 + bhi(q1.w) * n1 + bhi(q2.w) * n2 + bhi(q3.w) * n3;
    }
    for (; j < j1; ++j) {
        const unsigned int p0 = csrw[j];
        const float n0 = bhi(p0);
        const u32x4 q0 = hb4[(size_t)(p0 & 0xFFFF) * 16 + lane];
        a0 += blo(q0.x) * n0; a1 += bhi(q0.x) * n0;
        a2 += blo(q0.y) * n0; a3 += bhi(q0.y) * n0;
        a4 += blo(q0.z) * n0; a5 += bhi(q0.z) * n0;
        a6 += blo(q0.w) * n0; a7 += bhi(q0.w) * n0;
    }
    const float nd = degi_r[gi] * (1.0f - ALPHA_);
    const u32x4 xq = ((const u32x4*)xb)[(size_t)node * 16 + lane];
    u32x4 o;
    o.x = pack2(a0 * nd + ALPHA_ * blo(xq.x), a1 * nd + ALPHA_ * bhi(xq.x));
    o.y = pack2(a2 * nd + ALPHA_ * blo(xq.y), a3 * nd + ALPHA_ * bhi(xq.y));
    o.z = pack2(a4 * nd + ALPHA_ * blo(xq.z), a5 * nd + ALPHA_ * bhi(xq.z));
    o.w = pack2(a6 * nd + ALPHA_ * blo(xq.w), a7 * nd + ALPHA_ * bhi(xq.w));
    ((u32x4*)aggb)[(size_t)gi * 16 + lane] = o;
}

// ---------------- MFMA conv1: rst_r @ W1'_r + b1 -> leaky -> mean over r -> h1b ----------------
template<int LIN>
__global__ __launch_bounds__(256) void conv_mfma_kernel(
    const unsigned short* __restrict__ aggb,   // [R][N][128] bf16
    const unsigned short* __restrict__ WtG,    // [R][128][128] bf16, [n][k]
    const float* __restrict__ bias,            // [R,128]
    unsigned short* __restrict__ houtb)        // h1b
{
    __shared__ unsigned short WtL[DD * 136];   // 34816 B, stride 136 bf16 (17 uint4)
    uint4* WtL4 = (uint4*)WtL;
    const int tid  = threadIdx.x;
    const int wave = tid >> 6;
    const int lane = tid & 63;
    const int l15  = lane & 15;
    const int q    = lane >> 4;                // 0..3
    const int blockRow = blockIdx.x * 64;
    const int row0 = blockRow + wave * 16;
    const int arow = min(row0 + l15, NN - 1);  // A-frag row (clamped)

    f32x4 o[8];
    #pragma unroll
    for (int ct = 0; ct < 8; ++ct) o[ct] = (f32x4){0.f, 0.f, 0.f, 0.f};

    short8 a_cur[4], a_nxt[4];
    {
        const uint4* ap = (const uint4*)aggb + (size_t)arow * 16 + q;
        #pragma unroll
        for (int ks = 0; ks < 4; ++ks)
            a_cur[ks] = __builtin_bit_cast(short8, ap[ks * 4]);
    }

    for (int r = 0; r < RR; ++r) {
        __syncthreads();
        const uint4* wg = (const uint4*)(WtG + (size_t)r * DD * DD);
        for (int i = tid; i < DD * 16; i += 256)
            WtL4[(i >> 4) * 17 + (i & 15)] = wg[i];
        if (r + 1 < RR) {
            const uint4* ap = (const uint4*)aggb + ((size_t)(r + 1) * NN + arow) * 16 + q;
            #pragma unroll
            for (int ks = 0; ks < 4; ++ks)
                a_nxt[ks] = __builtin_bit_cast(short8, ap[ks * 4]);
        }
        __syncthreads();

        #pragma unroll
        for (int ct = 0; ct < 8; ++ct) {
            const float bv = bias[r * DD + ct * 16 + l15];
            f32x4 acc = (f32x4){bv, bv, bv, bv};
            const int nrow = ct * 16 + l15;
            #pragma unroll
            for (int ks = 0; ks < 4; ++ks) {
                const short8 b = __builtin_bit_cast(short8, WtL4[nrow * 17 + ks * 4 + q]);
                acc = __builtin_amdgcn_mfma_f32_16x16x32_bf16(a_cur[ks], b, acc, 0, 0, 0);
            }
            #pragma unroll
            for (int e = 0; e < 4; ++e) {
                float v = acc[e];
                v = v >= 0.f ? v : SLOPE_ * v;
                o[ct][e] += v * (1.0f / 3.0f);
            }
        }
        #pragma unroll
        for (int ks = 0; ks < 4; ++ks) a_cur[ks] = a_nxt[ks];
    }

    __syncthreads();
    unsigned short* tile = WtL;                // rows 0..63, stride 136
    #pragma unroll
    for (int ct = 0; ct < 8; ++ct) {
        const int col = ct * 16 + l15;
        #pragma unroll
        for (int e = 0; e < 4; ++e) {
            const int lrow = wave * 16 + q * 4 + e;
            tile[lrow * 136 + col] = f2b(o[ct][e]);
        }
    }
    __syncthreads();
    for (int i = tid; i < 64 * 16; i += 256) {
        const int lrow = i >> 4, c = i & 15;
        const int grow = blockRow + lrow;
        if (grow < NN)
            ((uint4*)houtb)[(size_t)grow * 16 + c] = WtL4[lrow * 17 + c];
    }
}

// ---------------- pgemm: P_r = h1b @ M_r (r=0..2), Q = ALPHA * x @ sum_r M_r  (all N x 64 bf16) ----
__global__ __launch_bounds__(512) void pgemm_kernel(
    const unsigned short* __restrict__ h1b,  // [N][128] bf16
    const unsigned short* __restrict__ xb,   // [N][128] bf16
    const unsigned short* __restrict__ MT,   // [R][64][128] bf16 (o-major, k inner)
    unsigned short* __restrict__ Pb,         // [R][N][64] bf16
    unsigned short* __restrict__ Qb)         // [N][64] bf16
{
    __shared__ unsigned short MTL[RR * 64 * 136];   // 52224 B, stride 136 (17 uint4)
    uint4* MTL4 = (uint4*)MTL;
    const int tid  = threadIdx.x;
    const int wave = tid >> 6;                 // 0..7
    const int lane = tid & 63;
    const int l15  = lane & 15;
    const int q    = lane >> 4;
    const int blockRow = blockIdx.x * 128;
    const int row0 = blockRow + wave * 16;
    const int arow = min(row0 + l15, NN - 1);

    {   // stage all three M^T matrices (3*64*16 = 3072 uint4)
        const uint4* mg = (const uint4*)MT;
        for (int i = tid; i < RR * 64 * 16; i += 512)
            MTL4[(i >> 4) * 17 + (i & 15)] = mg[i];
    }
    short8 ah[4], ax[4];
    {
        const uint4* hp = (const uint4*)h1b + (size_t)arow * 16 + q;
        const uint4* xp = (const uint4*)xb + (size_t)arow * 16 + q;
        #pragma unroll
        for (int ks = 0; ks < 4; ++ks) {
            ah[ks] = __builtin_bit_cast(short8, hp[ks * 4]);
            ax[ks] = __builtin_bit_cast(short8, xp[ks * 4]);
        }
    }
    __syncthreads();

    // P_r = h1 @ M_r
    for (int r = 0; r < RR; ++r) {
        #pragma unroll
        for (int ct = 0; ct < 4; ++ct) {
            f32x4 acc = (f32x4){0.f, 0.f, 0.f, 0.f};
            const int orow = r * 64 + ct * 16 + l15;
            #pragma unroll
            for (int ks = 0; ks < 4; ++ks) {
                const short8 b = __builtin_bit_cast(short8, MTL4[orow * 17 + ks * 4 + q]);
                acc = __builtin_amdgcn_mfma_f32_16x16x32_bf16(ah[ks], b, acc, 0, 0, 0);
            }
            #pragma unroll
            for (int e = 0; e < 4; ++e) {
                const int grow = row0 + q * 4 + e;
                if (grow < NN)
                    Pb[((size_t)r * NN + grow) * OUTD + ct * 16 + l15] = f2b(acc[e]);
            }
        }
    }
    // Q = ALPHA * x @ (M0+M1+M2)
    #pragma unroll
    for (int ct = 0; ct < 4; ++ct) {
        f32x4 acc = (f32x4){0.f, 0.f, 0.f, 0.f};
        for (int r = 0; r < RR; ++r) {
            const int orow = r * 64 + ct * 16 + l15;
            #pragma unroll
            for (int ks = 0; ks < 4; ++ks) {
                const short8 b = __builtin_bit_cast(short8, MTL4[orow * 17 + ks * 4 + q]);
                acc = __builtin_amdgcn_mfma_f32_16x16x32_bf16(ax[ks], b, acc, 0, 0, 0);
            }
        }
        #pragma unroll
        for (int e = 0; e < 4; ++e) {
            const int grow = row0 + q * 4 + e;
            if (grow < NN)
                Qb[(size_t)grow * OUTD + ct * 16 + l15] = f2b(acc[e] * ALPHA_);
        }
    }
}

// ---------------- pull64: out[v] = sum_r (1-a)*degi_r[v] * gather(P_r) + Q[v] + C ----------------
// (round-9-benched unroll-4 version; 16 lanes/node, 8B/lane, r-loop in registers)
__global__ __launch_bounds__(256) void pull64_kernel(
    const unsigned short* __restrict__ Pb,   // [R][N][64] bf16
    const unsigned short* __restrict__ Qb,   // [N][64] bf16
    const float* __restrict__ Cbuf,          // [64] f32
    const int* __restrict__ csrw, const int* __restrict__ off_g,
    const int* __restrict__ cnt_g, const float* __restrict__ degi_r,
    float* __restrict__ outf)                // [N][64] f32
{
    const int node = blockIdx.x * 16 + (threadIdx.x >> 4);
    const int lane = threadIdx.x & 15;
    const uint2* P2 = (const uint2*)Pb;
    float t0, t1, t2, t3;
    {
        const uint2 qq = ((const uint2*)Qb)[(size_t)node * 16 + lane];
        const float4 cv = ((const float4*)Cbuf)[lane];
        t0 = blo(qq.x) + cv.x; t1 = bhi(qq.x) + cv.y;
        t2 = blo(qq.y) + cv.z; t3 = bhi(qq.y) + cv.w;
    }
    for (int r = 0; r < RR; ++r) {
        const int gi = r * NN + node;
        const int j0 = off_g[gi];
        const int j1 = j0 + cnt_g[gi];
        const uint2* Pr = P2 + (size_t)r * NN * 16;
        float a0 = 0.f, a1 = 0.f, a2 = 0.f, a3 = 0.f;
        int j = j0;
        for (; j + 4 <= j1; j += 4) {
            const unsigned int p0 = csrw[j],     p1 = csrw[j + 1];
            const unsigned int p2 = csrw[j + 2], p3 = csrw[j + 3];
            const float n0 = bhi(p0), n1 = bhi(p1), n2 = bhi(p2), n3 = bhi(p3);
            const uint2 q0 = Pr[(size_t)(p0 & 0xFFFF) * 16 + lane];
            const uint2 q1 = Pr[(size_t)(p1 & 0xFFFF) * 16 + lane];
            const uint2 q2 = Pr[(size_t)(p2 & 0xFFFF) * 16 + lane];
            const uint2 q3 = Pr[(size_t)(p3 & 0xFFFF) * 16 + lane];
            a0 += blo(q0.x) * n0 + blo(q1.x) * n1 + blo(q2.x) * n2 + blo(q3.x) * n3;
            a1 += bhi(q0.x) * n0 + bhi(q1.x) * n1 + bhi(q2.x) * n2 + bhi(q3.x) * n3;
            a2 += blo(q0.y) * n0 + blo(q1.y) * n1 + blo(q2.y) * n2 + blo(q3.y) * n3;
            a3 += bhi(q0.y) * n0 + bhi(q1.y) * n1 + bhi(q2.y) * n2 + bhi(q3.y) * n3;
        }
        for (; j < j1; ++j) {
            const unsigned int p0 = csrw[j];
            const float n0 = bhi(p0);
            const uint2 q0 = Pr[(size_t)(p0 & 0xFFFF) * 16 + lane];
            a0 += blo(q0.x) * n0; a1 += bhi(q0.x) * n0;
            a2 += blo(q0.y) * n0; a3 += bhi(q0.y) * n0;
        }
        const float nd = degi_r[gi] * (1.0f - ALPHA_);
        t0 += a0 * nd; t1 += a1 * nd; t2 += a2 * nd; t3 += a3 * nd;
    }
    float4 ov; ov.x = t0; ov.y = t1; ov.z = t2; ov.w = t3;
    ((float4*)outf)[(size_t)node * 16 + lane] = ov;
}

extern "C" void kernel_launch(void* const* d_in, const int* in_sizes, int n_in,
                              void* d_out, int out_size, void* d_ws, size_t ws_size,
                              hipStream_t stream)
{
    const float* x    = (const float*)d_in[0];
    const int*   src  = (const int*)  d_in[1];
    const int*   dst  = (const int*)  d_in[2];
    const float* W1   = (const float*)d_in[3];
    const float* b1   = (const float*)d_in[4];
    const float* W2   = (const float*)d_in[5];
    const float* b2   = (const float*)d_in[6];
    const float* Wlin = (const float*)d_in[7];
    const float* blin = (const float*)d_in[8];
    float* out = (float*)d_out;

    // ws layout (4B units): bcnt_d[3*NBK] | bcnt_s(layout) | dego_r[3N] | degi_r[3N] |
    //   off_g[3N] | cnt_g[3N] | pad[2] | pairs_d[3*NBK*CAP] | pairs_s(layout u16 region) |
    //   xb | h1b | aggb (aliased by Pb+Qb after conv1) | Wt1 | Wt2 | WlT(layout) | MT | Cbuf
    int*   bcnt_d  = (int*)d_ws;
    int*   bcnt_s  = bcnt_d + RR * NBK;                // layout only
    float* dego_r  = (float*)(bcnt_s + RR * NBK);
    float* degi_r  = dego_r + RR * NN;
    int*   off_g   = (int*)(degi_r + RR * NN);
    int*   cnt_g   = off_g + RR * NN;
    int*   pairs_d = cnt_g + RR * NN + 2;    // +2 -> 16B alignment downstream
    unsigned short* pairs_s = (unsigned short*)(pairs_d + (size_t)RR * NBK * CAP);  // layout only
    unsigned short* xb   = pairs_s + (size_t)RR * NBK * CAPB;
    unsigned short* h1b  = xb + (size_t)NN * DD;
    unsigned short* aggb = h1b + (size_t)NN * DD;
    unsigned short* Wt1  = aggb + (size_t)RR * NN * DD;
    unsigned short* Wt2  = Wt1 + RR * DD * DD;
    unsigned short* WlT  = Wt2 + RR * DD * DD;         // layout only (unused)
    unsigned short* MT   = WlT + OUTD * DD;            // [R][64][128] bf16
    float*          Cbuf = (float*)(MT + RR * DD * OUTD);
    // Pb/Qb alias aggb region (aggb dead after conv1; stream-ordered safe):
    unsigned short* Pb = aggb;                          // RR*NN*64 u16 (9.6M of 19.2M)
    unsigned short* Qb = aggb + (size_t)RR * NN * OUTD; // NN*64 u16

    hipMemsetAsync(bcnt_d, 0, (size_t)RR * NBK * sizeof(int), stream);

    const int gemm_blocks = (NN + 63) / 64;

    // ---- graph preprocessing (ONE merged launch; same graph both layers) ----
    prep_kernel<<<NBINA + DEGB + CASTB, 1024, 0, stream>>>(
        src, dst, bcnt_d, pairs_d, dego_r, x, xb, W1, W2, Wlin, Wt1, Wt2,
        b2, blin, MT, Cbuf);
    sort_kernel<<<RR * NBK, 256, 0, stream>>>(
        pairs_d, bcnt_d, dego_r, off_g, cnt_g, degi_r);

    // ---- conv1: h1b = bf16( mean_r leaky( rst_r @ W1'_r + b1_r ) ) ----
    pull_all_kernel<<<RR * NPB, 256, 0, stream>>>(
        xb, xb, pairs_d, off_g, cnt_g, degi_r, aggb);
    conv_mfma_kernel<0><<<gemm_blocks, 256, 0, stream>>>(
        aggb, Wt1, b1, h1b);

    // ---- layer 2 via associativity: project h1 into 64-dim per relation, THEN gather ----
    pgemm_kernel<<<PGB, 512, 0, stream>>>(h1b, xb, MT, Pb, Qb);
    pull64_kernel<<<P64B, 256, 0, stream>>>(
        Pb, Qb, Cbuf, pairs_d, off_g, cnt_g, degi_r, out);
}

// Round 15
// 376.138 us; speedup vs baseline: 1.6147x; 1.0162x over previous
//
#include <hip/hip_runtime.h>

#define NN    50000
#define DD    128
#define RR    3
#define EE    800000
#define OUTD  64
#define BKT   128                 // nodes per bucket (dst and src binning)
#define NBK   391                 // ceil(NN/BKT)
#define CAP   2560                // per-bucket edge capacity, 4B dst-entries
#define CAPB  2560                // per-bucket edge capacity, 2B src-entries
#define CHUNK 8192                // edges per bin block (98 same-address reserve atomics/counter)
#define NCH   98                  // ceil(EE/CHUNK)
#define NPB   3125                // NN/16 pull blocks per relation
#define SETUPB 6250               // NN*DD/4/256 setup blocks
#define MCB   49                  // M-matrix (48) + C-vector (1) prep blocks
#define PGB   391                 // ceil(NN/128) pgemm blocks
#define P64B  3125                // NN/16 pull64 blocks
#define ALPHA_ 0.5f
#define SLOPE_ 0.01f
#define BETA1_ 0.6931471805599453f   // log(2)
#define BETA2_ 0.4054651081081644f   // log(1.5)

typedef __attribute__((ext_vector_type(8))) short short8;   // 8 bf16 = 4 VGPRs
typedef __attribute__((ext_vector_type(4))) float f32x4;
typedef __attribute__((ext_vector_type(4))) unsigned int u32x4;

__device__ __forceinline__ unsigned short f2b(float f) {   // fp32 -> bf16 RNE
    unsigned int u = __builtin_bit_cast(unsigned int, f);
    u += 0x7FFFu + ((u >> 16) & 1u);
    return (unsigned short)(u >> 16);
}
__device__ __forceinline__ unsigned int pack2(float lo, float hi) {
    return (unsigned int)f2b(lo) | ((unsigned int)f2b(hi) << 16);
}
__device__ __forceinline__ float blo(unsigned int w) { return __builtin_bit_cast(float, w << 16); }
__device__ __forceinline__ float bhi(unsigned int w) { return __builtin_bit_cast(float, w & 0xFFFF0000u); }

// ---------------- binning: phase-split LDS bucket-sort (A: by dst>>7, B: by src>>7) ----------------
__global__ __launch_bounds__(256) void bin_kernel(
    const int* __restrict__ src, const int* __restrict__ dst,
    int* __restrict__ bcnt_d, int* __restrict__ bcnt_s,
    int* __restrict__ pairs_d, unsigned short* __restrict__ pairs_s)
{
    __shared__ int hist[NBK];
    __shared__ int lbase[NBK];
    __shared__ int gdelta[NBK];
    __shared__ int lcur[NBK];
    __shared__ unsigned int staging[CHUNK];
    unsigned short* staging16 = (unsigned short*)staging;
    const int tid = threadIdx.x;
    const int blk = blockIdx.x;
    const int phase = (blk >= RR * NCH);
    const int rb = phase ? blk - RR * NCH : blk;
    const int r = rb / NCH;
    const int chunk = rb % NCH;
    const int e0 = chunk * CHUNK;
    const int n = min(CHUNK, EE - e0);
    const int* sp = src + (size_t)r * EE + e0;
    const int* dp = dst + (size_t)r * EE + e0;
    const int* kp = phase ? sp : dp;         // key stream for this phase

    for (int i = tid; i < NBK; i += 256) hist[i] = 0;
    __syncthreads();
    for (int i = tid; i < n; i += 256)
        atomicAdd(&hist[kp[i] >> 7], 1);
    __syncthreads();
    if (tid < 64) {
        int carry = 0;
        for (int c0 = 0; c0 < NBK; c0 += 64) {
            const int idx = c0 + tid;
            const int v = (idx < NBK) ? hist[idx] : 0;
            int incl = v;
            #pragma unroll
            for (int d = 1; d < 64; d <<= 1) {
                const int t = __shfl_up(incl, d, 64);
                if (tid >= d) incl += t;
            }
            if (idx < NBK) lbase[idx] = carry + incl - v;
            carry += __shfl(incl, 63, 64);
        }
    }
    __syncthreads();
    if (!phase) {
        for (int b = tid; b < NBK; b += 256) {
            lcur[b] = lbase[b];
            const int h = hist[b];
            if (h > 0) {
                const int gstart = (r * NBK + b) * CAP + atomicAdd(&bcnt_d[r * NBK + b], h);
                gdelta[b] = gstart - lbase[b];
            }
        }
        __syncthreads();
        for (int i = tid; i < n; i += 256) {
            const int d = dp[i];
            const int b = d >> 7;
            const int pos = atomicAdd(&lcur[b], 1);
            staging[pos] = (unsigned int)sp[i] | ((unsigned int)(d & 127) << 16)
                         | ((unsigned int)b << 23);
        }
        __syncthreads();
        for (int j = tid; j < n; j += 256) {
            const unsigned int v = staging[j];
            const int b = v >> 23;
            const int gi = gdelta[b] + j;
            const int lo = gi - (r * NBK + b) * CAP;
            if (lo < CAP) pairs_d[gi] = (int)(v & 0x7FFFFF);
        }
    } else {
        for (int b = tid; b < NBK; b += 256) {
            lcur[b] = lbase[b];
            const int h = hist[b];
            if (h > 0) {
                const int gstart = (r * NBK + b) * CAPB + atomicAdd(&bcnt_s[r * NBK + b], h);
                gdelta[b] = gstart - lbase[b];
            }
        }
        __syncthreads();
        for (int i = tid; i < n; i += 256) {
            const int s = sp[i];
            const int b = s >> 7;
            const int pos = atomicAdd(&lcur[b], 1);
            staging16[pos] = (unsigned short)((b << 7) | (s & 127));
        }
        __syncthreads();
        for (int j = tid; j < n; j += 256) {
            const unsigned short v = staging16[j];
            const int b = v >> 7;
            const int gi = gdelta[b] + j;
            const int lo = gi - (r * NBK + b) * CAPB;
            if (lo < CAPB) pairs_s[gi] = v;
        }
    }
}

// ---------------- merged: dego count | x cast / W' prep | M = W2'@Wlin/3 and C prep ----------------
__global__ __launch_bounds__(256) void dego_setup_kernel(
    const unsigned short* __restrict__ pairs_s, const int* __restrict__ bcnt_s,
    float* __restrict__ dego_r,
    const float* __restrict__ x, unsigned short* __restrict__ xb,
    const float* __restrict__ W1, const float* __restrict__ W2,
    const float* __restrict__ Wlin, unsigned short* __restrict__ Wt1,
    unsigned short* __restrict__ Wt2, unsigned short* __restrict__ WlT,
    const float* __restrict__ b2, const float* __restrict__ blin,
    unsigned short* __restrict__ MT, float* __restrict__ Cbuf)
{
    __shared__ int scnt[BKT];
    const int tid = threadIdx.x;
    const int blk = blockIdx.x;
    if (blk < RR * NBK) {
        const int n2 = min(bcnt_s[blk], CAPB);
        const unsigned short* ps = pairs_s + (size_t)blk * CAPB;
        if (tid < BKT) scnt[tid] = 0;
        __syncthreads();
        for (int i = tid; i < n2; i += 256)
            atomicAdd(&scnt[ps[i] & 127], 1);
        __syncthreads();
        if (tid < BKT) {
            const int r = blk / NBK;
            const int g = (blk % NBK) * BKT + tid;
            if (g < NN)
                dego_r[r * NN + g] = rsqrtf((float)max(scnt[tid], 1));
        }
    } else if (blk < RR * NBK + SETUPB) {
        const int i = (blk - RR * NBK) * 256 + tid;   // 0 .. NN*DD/4-1
        {
            const float4 v = ((const float4*)x)[i];
            ushort4 o;
            o.x = f2b(v.x); o.y = f2b(v.y); o.z = f2b(v.z); o.w = f2b(v.w);
            ((ushort4*)xb)[i] = o;
        }
        if (i < RR * DD * DD) {
            const int r = i >> 14, rem = i & 16383, nn = rem >> 7, k = rem & 127;
            const float diag = (k == nn) ? 1.0f : 0.0f;
            const float w1 = W1[r * DD * DD + k * DD + nn];
            Wt1[i] = f2b(BETA1_ * w1 + diag * (1.0f - BETA1_));
            const float w2 = W2[r * DD * DD + k * DD + nn];
            Wt2[i] = f2b((BETA2_ * w2 + diag * (1.0f - BETA2_)) * (1.0f / 3.0f));
        } else if (i < RR * DD * DD + OUTD * DD) {
            const int j = i - RR * DD * DD;
            const int nn = j >> 7, k = j & 127;
            WlT[j] = f2b(Wlin[k * OUTD + nn]);
        }
    } else {
        // ---- M_r^T[o][k] = ((1-b2)/3)*Wlin[k][o] + (b2/3)*sum_n W2[r][k][n]*Wlin[n][o]; C[o] ----
        const int mb = blk - RR * NBK - SETUPB;
        if (mb < MCB - 1) {
            const int base = (mb * 256 + tid) * 2;
            #pragma unroll
            for (int ii = 0; ii < 2; ++ii) {
                const int gidx = base + ii;           // flat = r*8192 + o*128 + k
                const int r = gidx >> 13;
                const int rem = gidx & 8191;
                const int o = rem >> 7, k = rem & 127;
                float s = 0.f;
                for (int nn = 0; nn < DD; ++nn)
                    s += W2[r * DD * DD + k * DD + nn] * Wlin[nn * OUTD + o];
                MT[gidx] = f2b((BETA2_ / 3.0f) * s + ((1.0f - BETA2_) / 3.0f) * Wlin[k * OUTD + o]);
            }
        } else {
            if (tid < OUTD) {
                float s = blin[tid];
                for (int nn = 0; nn < DD; ++nn) {
                    const float mb2 = (b2[nn] + b2[DD + nn] + b2[2 * DD + nn]) * (1.0f / 3.0f);
                    s += mb2 * Wlin[nn * OUTD + tid];
                }
                Cbuf[tid] = s;
            }
        }
    }
}

// ---------------- per-bucket counting sort (in place) -> weighted CSR + degi ----------------
__global__ __launch_bounds__(256) void sort_kernel(
    int* __restrict__ pairs_d, const int* __restrict__ bcnt_d,
    const float* __restrict__ dego_r,
    int* __restrict__ off_g, int* __restrict__ cnt_g, float* __restrict__ degi_r)
{
    __shared__ int stage[CAP];
    __shared__ int cnt[BKT];
    __shared__ int base[BKT];
    __shared__ int pos[BKT];
    const int tid = threadIdx.x;
    const int bid = blockIdx.x;              // r*NBK + b
    const int rr = bid / NBK;
    const int n = min(bcnt_d[bid], CAP);
    int* pp = pairs_d + (size_t)bid * CAP;
    const float* dego = dego_r + (size_t)rr * NN;
    if (tid < BKT) cnt[tid] = 0;
    __syncthreads();
    for (int i = tid; i < n; i += 256) {
        const int p = pp[i];
        stage[i] = p;
        atomicAdd(&cnt[p >> 16], 1);
    }
    __syncthreads();
    if (tid < 64) {
        int carry = 0;
        for (int c0 = 0; c0 < BKT; c0 += 64) {
            const int v = cnt[c0 + tid];
            int incl = v;
            #pragma unroll
            for (int d = 1; d < 64; d <<= 1) {
                const int t = __shfl_up(incl, d, 64);
                if (tid >= d) incl += t;
            }
            base[c0 + tid] = carry + incl - v;
            carry += __shfl(incl, 63, 64);
        }
    }
    __syncthreads();
    if (tid < BKT) {
        pos[tid] = base[tid];
        const int g = (bid % NBK) * BKT + tid;
        if (g < NN) {
            off_g[rr * NN + g] = bid * CAP + base[tid];
            cnt_g[rr * NN + g] = cnt[tid];
            degi_r[rr * NN + g] = rsqrtf((float)max(cnt[tid], 1));
        }
    }
    __syncthreads();
    for (int i = tid; i < n; i += 256) {
        const int p = stage[i];
        const int q = atomicAdd(&pos[p >> 16], 1);
        const int s = p & 0xFFFF;
        pp[q] = s | ((int)f2b(dego[s]) << 16);   // src + folded bf16 weight
    }
}

// ---------------- merged pull (all 3 relations): weighted-CSR bf16 gather + residual ----------------
// (round-6 verified: 16 lanes/node, 16B/lane, unroll-4, register accumulate)
__global__ __launch_bounds__(256) void pull_all_kernel(
    const unsigned short* __restrict__ hb,   // gather table [N,128] bf16
    const unsigned short* __restrict__ xb,   // residual [N,128] bf16
    const int* __restrict__ csrw, const int* __restrict__ off_g,
    const int* __restrict__ cnt_g, const float* __restrict__ degi_r,
    unsigned short* __restrict__ aggb)
{
    const int blk = blockIdx.x;              // r*NPB + nb
    const int r = blk / NPB;
    const int node = (blk % NPB) * 16 + (threadIdx.x >> 4);
    const int lane = threadIdx.x & 15;
    const int gi = r * NN + node;
    const int j0 = off_g[gi];
    const int j1 = j0 + cnt_g[gi];
    const u32x4* hb4 = (const u32x4*)hb;
    float a0 = 0.f, a1 = 0.f, a2 = 0.f, a3 = 0.f, a4 = 0.f, a5 = 0.f, a6 = 0.f, a7 = 0.f;
    int j = j0;
    for (; j + 4 <= j1; j += 4) {
        const unsigned int p0 = csrw[j],     p1 = csrw[j + 1];
        const unsigned int p2 = csrw[j + 2], p3 = csrw[j + 3];
        const float n0 = bhi(p0), n1 = bhi(p1), n2 = bhi(p2), n3 = bhi(p3);
        const u32x4 q0 = hb4[(size_t)(p0 & 0xFFFF) * 16 + lane];
        const u32x4 q1 = hb4[(size_t)(p1 & 0xFFFF) * 16 + lane];
        const u32x4 q2 = hb4[(size_t)(p2 & 0xFFFF) * 16 + lane];
        const u32x4 q3 = hb4[(size_t)(p3 & 0xFFFF) * 16 + lane];
        a0 += blo(q0.x) * n0 + blo(q1.x) * n1 + blo(q2.x) * n2 + blo(q3.x) * n3;
        a1 += bhi(q0.x) * n0 + bhi(q1.x) * n1 + bhi(q2.x) * n2 + bhi(q3.x) * n3;
        a2 += blo(q0.y) * n0 + blo(q1.y) * n1 + blo(q2.y) * n2 + blo(q3.y) * n3;
        a3 += bhi(q0.y) * n0 + bhi(q1.y) * n1 + bhi(q2.y) * n2 + bhi(q3.y) * n3;
        a4 += blo(q0.z) * n0 + blo(q1.z) * n1 + blo(q2.z) * n2 + blo(q3.z) * n3;
        a5 += bhi(q0.z) * n0 + bhi(q1.z) * n1 + bhi(q2.z) * n2 + bhi(q3.z) * n3;
        a6 += blo(q0.w) * n0 + blo(q1.w) * n1 + blo(q2.w) * n2 + blo(q3.w) * n3;
        a7 += bhi(q0.w) * n0 + bhi(q1.w) * n1 + bhi(q2.w) * n2 + bhi(q3.w) * n3;
    }
    for (; j < j1; ++j) {
        const unsigned int p0 = csrw[j];
        const float n0 = bhi(p0);
        const u32x4 q0 = hb4[(size_t)(p0 & 0xFFFF) * 16 + lane];
        a0 += blo(q0.x) * n0; a1 += bhi(q0.x) * n0;
        a2 += blo(q0.y) * n0; a3 += bhi(q0.y) * n0;
        a4 += blo(q0.z) * n0; a5 += bhi(q0.z) * n0;
        a6 += blo(q0.w) * n0; a7 += bhi(q0.w) * n0;
    }
    const float nd = degi_r[gi] * (1.0f - ALPHA_);
    const u32x4 xq = ((const u32x4*)xb)[(size_t)node * 16 + lane];
    u32x4 o;
    o.x = pack2(a0 * nd + ALPHA_ * blo(xq.x), a1 * nd + ALPHA_ * bhi(xq.x));
    o.y = pack2(a2 * nd + ALPHA_ * blo(xq.y), a3 * nd + ALPHA_ * bhi(xq.y));
    o.z = pack2(a4 * nd + ALPHA_ * blo(xq.z), a5 * nd + ALPHA_ * bhi(xq.z));
    o.w = pack2(a6 * nd + ALPHA_ * blo(xq.w), a7 * nd + ALPHA_ * bhi(xq.w));
    ((u32x4*)aggb)[(size_t)gi * 16 + lane] = o;
}

// ---------------- MFMA conv1: rst_r @ W1'_r + b1 -> leaky -> mean over r -> h1b ----------------
template<int LIN>
__global__ __launch_bounds__(256) void conv_mfma_kernel(
    const unsigned short* __restrict__ aggb,   // [R][N][128] bf16
    const unsigned short* __restrict__ WtG,    // [R][128][128] bf16, [n][k]
    const float* __restrict__ bias,            // [R,128]
    const unsigned short* __restrict__ WlT,    // unused (LIN=0)
    const float* __restrict__ blin,            // unused (LIN=0)
    unsigned short* __restrict__ houtb,        // h1b
    float* __restrict__ outf)                  // unused (LIN=0)
{
    __shared__ unsigned short WtL[DD * 136];   // 34816 B, stride 136 bf16 (17 uint4)
    uint4* WtL4 = (uint4*)WtL;
    const int tid  = threadIdx.x;
    const int wave = tid >> 6;
    const int lane = tid & 63;
    const int l15  = lane & 15;
    const int q    = lane >> 4;                // 0..3
    const int blockRow = blockIdx.x * 64;
    const int row0 = blockRow + wave * 16;
    const int arow = min(row0 + l15, NN - 1);  // A-frag row (clamped)

    f32x4 o[8];
    if (LIN) {
        #pragma unroll
        for (int ct = 0; ct < 8; ++ct) {
            const int col = ct * 16 + l15;
            const float bv = (bias[col] + bias[DD + col] + bias[2 * DD + col]) * (1.0f / 3.0f);
            o[ct] = (f32x4){bv, bv, bv, bv};
        }
    } else {
        #pragma unroll
        for (int ct = 0; ct < 8; ++ct) o[ct] = (f32x4){0.f, 0.f, 0.f, 0.f};
    }

    short8 a_cur[4], a_nxt[4];
    {
        const uint4* ap = (const uint4*)aggb + (size_t)arow * 16 + q;
        #pragma unroll
        for (int ks = 0; ks < 4; ++ks)
            a_cur[ks] = __builtin_bit_cast(short8, ap[ks * 4]);
    }

    for (int r = 0; r < RR; ++r) {
        __syncthreads();
        const uint4* wg = (const uint4*)(WtG + (size_t)r * DD * DD);
        for (int i = tid; i < DD * 16; i += 256)
            WtL4[(i >> 4) * 17 + (i & 15)] = wg[i];
        if (r + 1 < RR) {
            const uint4* ap = (const uint4*)aggb + ((size_t)(r + 1) * NN + arow) * 16 + q;
            #pragma unroll
            for (int ks = 0; ks < 4; ++ks)
                a_nxt[ks] = __builtin_bit_cast(short8, ap[ks * 4]);
        }
        __syncthreads();

        #pragma unroll
        for (int ct = 0; ct < 8; ++ct) {
            f32x4 acc;
            if (LIN) {
                acc = o[ct];
            } else {
                const float bv = bias[r * DD + ct * 16 + l15];
                acc = (f32x4){bv, bv, bv, bv};
            }
            const int nrow = ct * 16 + l15;
            #pragma unroll
            for (int ks = 0; ks < 4; ++ks) {
                const short8 b = __builtin_bit_cast(short8, WtL4[nrow * 17 + ks * 4 + q]);
                acc = __builtin_amdgcn_mfma_f32_16x16x32_bf16(a_cur[ks], b, acc, 0, 0, 0);
            }
            if (LIN) {
                o[ct] = acc;
            } else {
                #pragma unroll
                for (int e = 0; e < 4; ++e) {
                    float v = acc[e];
                    v = v >= 0.f ? v : SLOPE_ * v;
                    o[ct][e] += v * (1.0f / 3.0f);
                }
            }
        }
        #pragma unroll
        for (int ks = 0; ks < 4; ++ks) a_cur[ks] = a_nxt[ks];
    }

    __syncthreads();
    unsigned short* tile = WtL;                // rows 0..63, stride 136
    #pragma unroll
    for (int ct = 0; ct < 8; ++ct) {
        const int col = ct * 16 + l15;
        #pragma unroll
        for (int e = 0; e < 4; ++e) {
            const int lrow = wave * 16 + q * 4 + e;
            tile[lrow * 136 + col] = f2b(o[ct][e]);
        }
    }
    __syncthreads();
    for (int i = tid; i < 64 * 16; i += 256) {
        const int lrow = i >> 4, c = i & 15;
        const int grow = blockRow + lrow;
        if (grow < NN)
            ((uint4*)houtb)[(size_t)grow * 16 + c] = WtL4[lrow * 17 + c];
    }
}

// ---------------- pgemm: P_r = h1b @ M_r (r=0..2), Q = ALPHA * x @ sum_r M_r  (all N x 64 bf16) ----
__global__ __launch_bounds__(512) void pgemm_kernel(
    const unsigned short* __restrict__ h1b,  // [N][128] bf16
    const unsigned short* __restrict__ xb,   // [N][128] bf16
    const unsigned short* __restrict__ MT,   // [R][64][128] bf16 (o-major, k inner)
    unsigned short* __restrict__ Pb,         // [R][N][64] bf16
    unsigned short* __restrict__ Qb)         // [N][64] bf16
{
    __shared__ unsigned short MTL[RR * 64 * 136];   // 52224 B, stride 136 (17 uint4)
    uint4* MTL4 = (uint4*)MTL;
    const int tid  = threadIdx.x;
    const int wave = tid >> 6;                 // 0..7
    const int lane = tid & 63;
    const int l15  = lane & 15;
    const int q    = lane >> 4;
    const int blockRow = blockIdx.x * 128;
    const int row0 = blockRow + wave * 16;
    const int arow = min(row0 + l15, NN - 1);

    {   // stage all three M^T matrices (3*64*16 = 3072 uint4)
        const uint4* mg = (const uint4*)MT;
        for (int i = tid; i < RR * 64 * 16; i += 512)
            MTL4[(i >> 4) * 17 + (i & 15)] = mg[i];
    }
    short8 ah[4], ax[4];
    {
        const uint4* hp = (const uint4*)h1b + (size_t)arow * 16 + q;
        const uint4* xp = (const uint4*)xb + (size_t)arow * 16 + q;
        #pragma unroll
        for (int ks = 0; ks < 4; ++ks) {
            ah[ks] = __builtin_bit_cast(short8, hp[ks * 4]);
            ax[ks] = __builtin_bit_cast(short8, xp[ks * 4]);
        }
    }
    __syncthreads();

    // P_r = h1 @ M_r
    for (int r = 0; r < RR; ++r) {
        #pragma unroll
        for (int ct = 0; ct < 4; ++ct) {
            f32x4 acc = (f32x4){0.f, 0.f, 0.f, 0.f};
            const int orow = r * 64 + ct * 16 + l15;
            #pragma unroll
            for (int ks = 0; ks < 4; ++ks) {
                const short8 b = __builtin_bit_cast(short8, MTL4[orow * 17 + ks * 4 + q]);
                acc = __builtin_amdgcn_mfma_f32_16x16x32_bf16(ah[ks], b, acc, 0, 0, 0);
            }
            #pragma unroll
            for (int e = 0; e < 4; ++e) {
                const int grow = row0 + q * 4 + e;
                if (grow < NN)
                    Pb[((size_t)r * NN + grow) * OUTD + ct * 16 + l15] = f2b(acc[e]);
            }
        }
    }
    // Q = ALPHA * x @ (M0+M1+M2)
    #pragma unroll
    for (int ct = 0; ct < 4; ++ct) {
        f32x4 acc = (f32x4){0.f, 0.f, 0.f, 0.f};
        for (int r = 0; r < RR; ++r) {
            const int orow = r * 64 + ct * 16 + l15;
            #pragma unroll
            for (int ks = 0; ks < 4; ++ks) {
                const short8 b = __builtin_bit_cast(short8, MTL4[orow * 17 + ks * 4 + q]);
                acc = __builtin_amdgcn_mfma_f32_16x16x32_bf16(ax[ks], b, acc, 0, 0, 0);
            }
        }
        #pragma unroll
        for (int e = 0; e < 4; ++e) {
            const int grow = row0 + q * 4 + e;
            if (grow < NN)
                Qb[(size_t)grow * OUTD + ct * 16 + l15] = f2b(acc[e] * ALPHA_);
        }
    }
}

// ---------------- pull64: out[v] = sum_r (1-a)*degi_r[v] * gather(P_r) + Q[v] + C ----------------
// 16 lanes/node, 8B/lane (row = 128B = one L2 line), r-loop accumulated in registers (no atomics).
__global__ __launch_bounds__(256) void pull64_kernel(
    const unsigned short* __restrict__ Pb,   // [R][N][64] bf16
    const unsigned short* __restrict__ Qb,   // [N][64] bf16
    const float* __restrict__ Cbuf,          // [64] f32
    const int* __restrict__ csrw, const int* __restrict__ off_g,
    const int* __restrict__ cnt_g, const float* __restrict__ degi_r,
    float* __restrict__ outf)                // [N][64] f32
{
    const int node = blockIdx.x * 16 + (threadIdx.x >> 4);
    const int lane = threadIdx.x & 15;
    const uint2* P2 = (const uint2*)Pb;
    float t0, t1, t2, t3;
    {
        const uint2 qq = ((const uint2*)Qb)[(size_t)node * 16 + lane];
        const float4 cv = ((const float4*)Cbuf)[lane];
        t0 = blo(qq.x) + cv.x; t1 = bhi(qq.x) + cv.y;
        t2 = blo(qq.y) + cv.z; t3 = bhi(qq.y) + cv.w;
    }
    for (int r = 0; r < RR; ++r) {
        const int gi = r * NN + node;
        const int j0 = off_g[gi];
        const int j1 = j0 + cnt_g[gi];
        const uint2* Pr = P2 + (size_t)r * NN * 16;
        float a0 = 0.f, a1 = 0.f, a2 = 0.f, a3 = 0.f;
        int j = j0;
        for (; j + 4 <= j1; j += 4) {
            const unsigned int p0 = csrw[j],     p1 = csrw[j + 1];
            const unsigned int p2 = csrw[j + 2], p3 = csrw[j + 3];
            const float n0 = bhi(p0), n1 = bhi(p1), n2 = bhi(p2), n3 = bhi(p3);
            const uint2 q0 = Pr[(size_t)(p0 & 0xFFFF) * 16 + lane];
            const uint2 q1 = Pr[(size_t)(p1 & 0xFFFF) * 16 + lane];
            const uint2 q2 = Pr[(size_t)(p2 & 0xFFFF) * 16 + lane];
            const uint2 q3 = Pr[(size_t)(p3 & 0xFFFF) * 16 + lane];
            a0 += blo(q0.x) * n0 + blo(q1.x) * n1 + blo(q2.x) * n2 + blo(q3.x) * n3;
            a1 += bhi(q0.x) * n0 + bhi(q1.x) * n1 + bhi(q2.x) * n2 + bhi(q3.x) * n3;
            a2 += blo(q0.y) * n0 + blo(q1.y) * n1 + blo(q2.y) * n2 + blo(q3.y) * n3;
            a3 += bhi(q0.y) * n0 + bhi(q1.y) * n1 + bhi(q2.y) * n2 + bhi(q3.y) * n3;
        }
        for (; j < j1; ++j) {
            const unsigned int p0 = csrw[j];
            const float n0 = bhi(p0);
            const uint2 q0 = Pr[(size_t)(p0 & 0xFFFF) * 16 + lane];
            a0 += blo(q0.x) * n0; a1 += bhi(q0.x) * n0;
            a2 += blo(q0.y) * n0; a3 += bhi(q0.y) * n0;
        }
        const float nd = degi_r[gi] * (1.0f - ALPHA_);
        t0 += a0 * nd; t1 += a1 * nd; t2 += a2 * nd; t3 += a3 * nd;
    }
    float4 ov; ov.x = t0; ov.y = t1; ov.z = t2; ov.w = t3;
    ((float4*)outf)[(size_t)node * 16 + lane] = ov;
}

extern "C" void kernel_launch(void* const* d_in, const int* in_sizes, int n_in,
                              void* d_out, int out_size, void* d_ws, size_t ws_size,
                              hipStream_t stream)
{
    const float* x    = (const float*)d_in[0];
    const int*   src  = (const int*)  d_in[1];
    const int*   dst  = (const int*)  d_in[2];
    const float* W1   = (const float*)d_in[3];
    const float* b1   = (const float*)d_in[4];
    const float* W2   = (const float*)d_in[5];
    const float* b2   = (const float*)d_in[6];
    const float* Wlin = (const float*)d_in[7];
    const float* blin = (const float*)d_in[8];
    float* out = (float*)d_out;

    // ws layout (4B units): bcnt_d[3*NBK] | bcnt_s[3*NBK] | dego_r[3N] | degi_r[3N] |
    //   off_g[3N] | cnt_g[3N] | pad[2] | pairs_d[3*NBK*CAP] | pairs_s(u16) |
    //   xb | h1b | aggb (later aliased by Pb+Qb) | Wt1 | Wt2 | WlT | MT | Cbuf
    int*   bcnt_d  = (int*)d_ws;
    int*   bcnt_s  = bcnt_d + RR * NBK;
    float* dego_r  = (float*)(bcnt_s + RR * NBK);
    float* degi_r  = dego_r + RR * NN;
    int*   off_g   = (int*)(degi_r + RR * NN);
    int*   cnt_g   = off_g + RR * NN;
    int*   pairs_d = cnt_g + RR * NN + 2;    // +2 -> 16B alignment downstream
    unsigned short* pairs_s = (unsigned short*)(pairs_d + (size_t)RR * NBK * CAP);
    unsigned short* xb   = pairs_s + (size_t)RR * NBK * CAPB;
    unsigned short* h1b  = xb + (size_t)NN * DD;
    unsigned short* aggb = h1b + (size_t)NN * DD;
    unsigned short* Wt1  = aggb + (size_t)RR * NN * DD;
    unsigned short* Wt2  = Wt1 + RR * DD * DD;
    unsigned short* WlT  = Wt2 + RR * DD * DD;
    unsigned short* MT   = WlT + OUTD * DD;            // [R][64][128] bf16
    float*          Cbuf = (float*)(MT + RR * DD * OUTD);
    // Pb/Qb alias aggb region (aggb dead after conv1; stream-ordered safe):
    unsigned short* Pb = aggb;                          // RR*NN*64 u16 (9.6M of 19.2M)
    unsigned short* Qb = aggb + (size_t)RR * NN * OUTD; // NN*64 u16

    hipMemsetAsync(bcnt_d, 0, (size_t)2 * RR * NBK * sizeof(int), stream);

    const int gemm_blocks = (NN + 63) / 64;

    // ---- graph preprocessing (once; same graph both layers) ----
    bin_kernel<<<2 * RR * NCH, 256, 0, stream>>>(src, dst, bcnt_d, bcnt_s, pairs_d, pairs_s);
    dego_setup_kernel<<<RR * NBK + SETUPB + MCB, 256, 0, stream>>>(
        pairs_s, bcnt_s, dego_r, x, xb, W1, W2, Wlin, Wt1, Wt2, WlT, b2, blin, MT, Cbuf);
    sort_kernel<<<RR * NBK, 256, 0, stream>>>(
        pairs_d, bcnt_d, dego_r, off_g, cnt_g, degi_r);

    // ---- conv1: h1b = bf16( mean_r leaky( rst_r @ W1'_r + b1_r ) ) ----
    pull_all_kernel<<<RR * NPB, 256, 0, stream>>>(
        xb, xb, pairs_d, off_g, cnt_g, degi_r, aggb);
    conv_mfma_kernel<0><<<gemm_blocks, 256, 0, stream>>>(
        aggb, Wt1, b1, nullptr, nullptr, h1b, nullptr);

    // ---- layer 2 via associativity: project h1 into 64-dim per relation, THEN gather ----
    pgemm_kernel<<<PGB, 512, 0, stream>>>(h1b, xb, MT, Pb, Qb);
    pull64_kernel<<<P64B, 256, 0, stream>>>(
        Pb, Qb, Cbuf, pairs_d, off_g, cnt_g, degi_r, out);
}